// Round 2
// baseline (428.337 us; speedup 1.0000x reference)
//
#include <hip/hip_runtime.h>

typedef _Float16 f16;
typedef _Float16 f16x8 __attribute__((ext_vector_type(8)));
typedef float f32x4 __attribute__((ext_vector_type(4)));

#define H_ 12
#define B_ 4
#define S_ 2048
#define DM 768
#define DK 64

__device__ __forceinline__ f16 f2h(float f) { return (f16)f; }

// ---------------- prep kernels ----------------

__global__ __launch_bounds__(256) void cast_x_kernel(const float* __restrict__ x,
                                                     f16* __restrict__ xb, int n4) {
  int i = blockIdx.x * 256 + threadIdx.x;
  if (i < n4) {
    float4 v = ((const float4*)x)[i];
    f16 h0 = f2h(v.x), h1 = f2h(v.y), h2 = f2h(v.z), h3 = f2h(v.w);
    union { f16 h[4]; uint2 u; } pk;
    pk.h[0] = h0; pk.h[1] = h1; pk.h[2] = h2; pk.h[3] = h3;
    ((uint2*)xb)[i] = pk.u;
  }
}

// Wt[(which*768 + h*64 + c) * 768 + m] = W_{which}[h][m][c]   (B^T layout, f16)
__global__ __launch_bounds__(256) void prep_wqkv_kernel(const float* __restrict__ WQ,
                                                        const float* __restrict__ WK,
                                                        const float* __restrict__ WV,
                                                        f16* __restrict__ Wt) {
  int id = blockIdx.x * 256 + threadIdx.x;  // 0 .. 2304*768-1 (exact)
  int R = id / DM, m = id - R * DM;
  const float* W = (R < 768) ? WQ : (R < 1536) ? WK : WV;
  int rr = (R >= 1536) ? R - 1536 : (R >= 768) ? R - 768 : R;
  int h = rr >> 6, c = rr & 63;
  Wt[id] = f2h(W[(h * DM + m) * DK + c]);
}

// Wot[d*768 + n] = W_O[n][d]   (B^T layout for out-proj, f16)
__global__ __launch_bounds__(256) void prep_wo_kernel(const float* __restrict__ WO,
                                                      f16* __restrict__ Wt) {
  int id = blockIdx.x * 256 + threadIdx.x;  // 0..768*768-1 (exact)
  int d = id / DM, n = id - d * DM;
  Wt[id] = f2h(WO[n * DM + d]);
}

// ---------------- GEMM: C[M,N] = A[M,K] * Bt[N,K]^T, K=768 ----------------
// MODE 0: fp32 out, row-major [M,N]
// MODE 1: f16 out scattered to qkv layout: which = n/768, h=(n%768)>>6, k=n&63,
//         b=m>>11, s=m&2047  ->  Cq[which*HBSD + ((h*B+b)*S+s)*64 + k]
template <int MODE>
__global__ __launch_bounds__(256) void gemm_bt_kernel(const f16* __restrict__ A,
                                                      const f16* __restrict__ Bt,
                                                      float* __restrict__ Cf,
                                                      f16* __restrict__ Cq, int N) {
  constexpr int K = 768;
  __shared__ f16 As[128 * 40];  // 32 k + 8 pad (keeps 16B align, 2-way-bank only)
  __shared__ f16 Bs[128 * 40];
  const int t = threadIdx.x;
  const int m0 = blockIdx.y * 128, n0 = blockIdx.x * 128;
  const int lane = t & 63, wave = t >> 6;
  const int l15 = lane & 15, quad = lane >> 4;
  const int m_off = (wave & 1) * 64, n_off = (wave >> 1) * 64;
  const int srow = t >> 2, skc = (t & 3) * 8;
  const f16* Ag = A + (size_t)(m0 + srow) * K + skc;
  const f16* Bg = Bt + (size_t)(n0 + srow) * K + skc;
  f32x4 acc[4][4];
  const f32x4 z4 = {0.f, 0.f, 0.f, 0.f};
  for (int i = 0; i < 4; i++)
    for (int j = 0; j < 4; j++) acc[i][j] = z4;

  for (int kt = 0; kt < K; kt += 32) {
    uint4 a0 = *(const uint4*)(Ag + kt);
    uint4 a1 = *(const uint4*)(Ag + (size_t)64 * K + kt);
    uint4 b0 = *(const uint4*)(Bg + kt);
    uint4 b1 = *(const uint4*)(Bg + (size_t)64 * K + kt);
    __syncthreads();
    *(uint4*)&As[srow * 40 + skc] = a0;
    *(uint4*)&As[(srow + 64) * 40 + skc] = a1;
    *(uint4*)&Bs[srow * 40 + skc] = b0;
    *(uint4*)&Bs[(srow + 64) * 40 + skc] = b1;
    __syncthreads();
    f16x8 af[4], bfr[4];
#pragma unroll
    for (int i = 0; i < 4; i++)
      af[i] = *(const f16x8*)&As[(m_off + i * 16 + l15) * 40 + quad * 8];
#pragma unroll
    for (int i = 0; i < 4; i++)
      bfr[i] = *(const f16x8*)&Bs[(n_off + i * 16 + l15) * 40 + quad * 8];
#pragma unroll
    for (int mi = 0; mi < 4; mi++)
#pragma unroll
      for (int ni = 0; ni < 4; ni++)
        acc[mi][ni] = __builtin_amdgcn_mfma_f32_16x16x32_f16(af[mi], bfr[ni],
                                                             acc[mi][ni], 0, 0, 0);
  }

  if (MODE == 0) {
#pragma unroll
    for (int mi = 0; mi < 4; mi++) {
      int row = m0 + m_off + mi * 16 + quad * 4;
#pragma unroll
      for (int ni = 0; ni < 4; ni++) {
        int col = n0 + n_off + ni * 16 + l15;
#pragma unroll
        for (int r = 0; r < 4; r++) Cf[(size_t)(row + r) * N + col] = acc[mi][ni][r];
      }
    }
  } else {
#pragma unroll
    for (int mi = 0; mi < 4; mi++) {
#pragma unroll
      for (int ni = 0; ni < 4; ni++) {
        int n = n0 + n_off + ni * 16 + l15;
        int which = n / DM;
        int rr = n - which * DM;
        int h = rr >> 6, kk = rr & 63;
#pragma unroll
        for (int r = 0; r < 4; r++) {
          int m = m0 + m_off + mi * 16 + quad * 4 + r;
          int b = m >> 11, s = m & 2047;
          size_t dst = (size_t)which * ((size_t)H_ * B_ * S_ * DK) +
                       ((size_t)((h * B_ + b) * S_ + s)) * DK + kk;
          Cq[dst] = f2h(acc[mi][ni][r]);
        }
      }
    }
  }
}

// ---------------- flash attention ----------------
// grid (S/64, B, H), 256 threads (4 waves x 16 q-rows).
// Q/K/V in [h][b][s][64] f16. Output multi_head f16 [b][q][h*64+v].
__global__ __launch_bounds__(256) void flash_kernel(const f16* __restrict__ Qg,
                                                    const f16* __restrict__ Kg,
                                                    const f16* __restrict__ Vg,
                                                    f16* __restrict__ MH) {
  const int qb = blockIdx.x, b = blockIdx.y, h = blockIdx.z;
  const size_t base = ((size_t)(h * B_ + b) * S_) * DK;
  const f16* Qp = Qg + base;
  const f16* Kp = Kg + base;
  const f16* Vp = Vg + base;

  __shared__ f16 Qs[64 * 72];   // [q][d], pad 72
  __shared__ f16 Ks[64 * 72];   // [kv][d]
  __shared__ f16 Vts[64 * 72];  // [v][kv]  (transposed V)
  __shared__ f16 Ps[4][16 * 72];  // per-wave P tile [q16][kv64]

  const int t = threadIdx.x, lane = t & 63, w = t >> 6;
  const int l15 = lane & 15, quad = lane >> 4;
  const int q0 = qb * 64;

  // stage Q (64 rows x 64 d)
  for (int i = 0; i < 2; i++) {
    int c = t + i * 256, row = c >> 3, kc = (c & 7) * 8;
    *(uint4*)&Qs[row * 72 + kc] = *(const uint4*)(Qp + (size_t)(q0 + row) * DK + kc);
  }

  float mrow[4] = {-1e30f, -1e30f, -1e30f, -1e30f};
  float lrow[4] = {0.f, 0.f, 0.f, 0.f};
  f32x4 oacc[4];
  const f32x4 z4 = {0.f, 0.f, 0.f, 0.f};
  for (int i = 0; i < 4; i++) oacc[i] = z4;

  for (int kt = 0; kt <= qb; kt++) {
    const int kv0 = kt * 64;
    __syncthreads();  // previous tile's MFMA reads done before overwrite
    for (int i = 0; i < 2; i++) {
      int c = t + i * 256, row = c >> 3, kc = (c & 7) * 8;
      *(uint4*)&Ks[row * 72 + kc] = *(const uint4*)(Kp + (size_t)(kv0 + row) * DK + kc);
      uint4 vv = *(const uint4*)(Vp + (size_t)(kv0 + row) * DK + kc);
      const f16* vs = (const f16*)&vv;
#pragma unroll
      for (int j = 0; j < 8; j++) Vts[(kc + j) * 72 + row] = vs[j];
    }
    __syncthreads();

    // S = Q K^T for this wave's 16 q-rows
    f32x4 sa[4];
    for (int i = 0; i < 4; i++) sa[i] = z4;
#pragma unroll
    for (int kc2 = 0; kc2 < 2; kc2++) {
      f16x8 aq = *(const f16x8*)&Qs[(w * 16 + l15) * 72 + kc2 * 32 + quad * 8];
#pragma unroll
      for (int ni = 0; ni < 4; ni++) {
        f16x8 bk = *(const f16x8*)&Ks[(ni * 16 + l15) * 72 + kc2 * 32 + quad * 8];
        sa[ni] = __builtin_amdgcn_mfma_f32_16x16x32_f16(aq, bk, sa[ni], 0, 0, 0);
      }
    }

    // scale + causal mask (only diagonal tile has masked cols)
    const bool diag = (kt == qb);
#pragma unroll
    for (int ni = 0; ni < 4; ni++) {
      int kv = kv0 + ni * 16 + l15;
#pragma unroll
      for (int r = 0; r < 4; r++) {
        float s = sa[ni][r] * 0.125f;
        if (diag) {
          int q = q0 + w * 16 + quad * 4 + r;
          if (kv > q) s = -1e30f;
        }
        sa[ni][r] = s;
      }
    }

    // online softmax per q-row (rows live on the 16 lanes of each quad)
    float alpha[4];
#pragma unroll
    for (int r = 0; r < 4; r++) {
      float mx = fmaxf(fmaxf(sa[0][r], sa[1][r]), fmaxf(sa[2][r], sa[3][r]));
      mx = fmaxf(mx, __shfl_xor(mx, 1));
      mx = fmaxf(mx, __shfl_xor(mx, 2));
      mx = fmaxf(mx, __shfl_xor(mx, 4));
      mx = fmaxf(mx, __shfl_xor(mx, 8));
      float mn = fmaxf(mrow[r], mx);
      alpha[r] = __expf(mrow[r] - mn);
      mrow[r] = mn;
      float rs = 0.f;
#pragma unroll
      for (int ni = 0; ni < 4; ni++) {
        float p = __expf(sa[ni][r] - mn);
        sa[ni][r] = p;
        rs += p;
      }
      rs += __shfl_xor(rs, 1);
      rs += __shfl_xor(rs, 2);
      rs += __shfl_xor(rs, 4);
      rs += __shfl_xor(rs, 8);
      lrow[r] = lrow[r] * alpha[r] + rs;
    }

    // P: C-layout -> LDS -> A-layout (m120 recipe)
#pragma unroll
    for (int ni = 0; ni < 4; ni++)
#pragma unroll
      for (int r = 0; r < 4; r++)
        Ps[w][(quad * 4 + r) * 72 + ni * 16 + l15] = f2h(sa[ni][r]);
#pragma unroll
    for (int ni = 0; ni < 4; ni++)
#pragma unroll
      for (int r = 0; r < 4; r++) oacc[ni][r] *= alpha[r];
    __syncthreads();

    // O += P V
#pragma unroll
    for (int kc2 = 0; kc2 < 2; kc2++) {
      f16x8 ap = *(const f16x8*)&Ps[w][l15 * 72 + kc2 * 32 + quad * 8];
#pragma unroll
      for (int ni = 0; ni < 4; ni++) {
        f16x8 bv = *(const f16x8*)&Vts[(ni * 16 + l15) * 72 + kc2 * 32 + quad * 8];
        oacc[ni] = __builtin_amdgcn_mfma_f32_16x16x32_f16(ap, bv, oacc[ni], 0, 0, 0);
      }
    }
  }

  // normalize + write multi_head [b][q][h*64+v]
#pragma unroll
  for (int r = 0; r < 4; r++) {
    float inv = 1.0f / lrow[r];
    int q = q0 + w * 16 + quad * 4 + r;
    size_t rowbase = ((size_t)b * S_ + q) * DM + h * DK;
#pragma unroll
    for (int ni = 0; ni < 4; ni++)
      MH[rowbase + ni * 16 + l15] = f2h(oacc[ni][r] * inv);
  }
}

// ---------------- launch ----------------

extern "C" void kernel_launch(void* const* d_in, const int* in_sizes, int n_in,
                              void* d_out, int out_size, void* d_ws, size_t ws_size,
                              hipStream_t stream) {
  const float* residual = (const float*)d_in[0];
  const float* WQ = (const float*)d_in[1];
  const float* WK = (const float*)d_in[2];
  const float* WV = (const float*)d_in[3];
  const float* WO = (const float*)d_in[4];
  float* out = (float*)d_out;

  char* ws = (char*)d_ws;
  size_t off = 0;
  auto alloc = [&](size_t bytes) {
    void* p = ws + off;
    off += (bytes + 255) & ~(size_t)255;
    return p;
  };
  f16* xb = (f16*)alloc((size_t)B_ * S_ * DM * 2);            // 12.6 MB
  f16* wqkv = (f16*)alloc((size_t)3 * DM * DM * 2);           // 3.5 MB
  f16* wot = (f16*)alloc((size_t)DM * DM * 2);                // 1.2 MB
  f16* qkv = (f16*)alloc((size_t)3 * H_ * B_ * S_ * DK * 2);  // 37.7 MB
  f16* mh = (f16*)alloc((size_t)B_ * S_ * DM * 2);            // 12.6 MB
  // total ~67.6 MB of d_ws

  cast_x_kernel<<<(B_ * S_ * DM / 4 + 255) / 256, 256, 0, stream>>>(residual, xb,
                                                                    B_ * S_ * DM / 4);
  prep_wqkv_kernel<<<(3 * DM * DM) / 256, 256, 0, stream>>>(WQ, WK, WV, wqkv);
  prep_wo_kernel<<<(DM * DM) / 256, 256, 0, stream>>>(WO, wot);

  gemm_bt_kernel<1><<<dim3(3 * DM / 128, B_ * S_ / 128), 256, 0, stream>>>(
      xb, wqkv, nullptr, qkv, 3 * DM);

  f16* qbuf = qkv;
  f16* kbuf = qkv + (size_t)H_ * B_ * S_ * DK;
  f16* vbuf = kbuf + (size_t)H_ * B_ * S_ * DK;
  flash_kernel<<<dim3(S_ / 64, B_, H_), 256, 0, stream>>>(qbuf, kbuf, vbuf, mh);

  gemm_bt_kernel<0><<<dim3(DM / 128, B_ * S_ / 128), 256, 0, stream>>>(mh, wot, out,
                                                                       nullptr, DM);
}

// Round 3
// 402.634 us; speedup vs baseline: 1.0638x; 1.0638x over previous
//
#include <hip/hip_runtime.h>

typedef _Float16 f16;
typedef _Float16 f16x8 __attribute__((ext_vector_type(8)));
typedef float f32x4 __attribute__((ext_vector_type(4)));

#define H_ 12
#define B_ 4
#define S_ 2048
#define DM 768
#define DK 64

__device__ __forceinline__ f16 f2h(float f) { return (f16)f; }

// ---------------- prep kernels ----------------

__global__ __launch_bounds__(256) void cast_x_kernel(const float* __restrict__ x,
                                                     f16* __restrict__ xb, int n4) {
  int i = blockIdx.x * 256 + threadIdx.x;
  if (i < n4) {
    float4 v = ((const float4*)x)[i];
    union { f16 h[4]; uint2 u; } pk;
    pk.h[0] = f2h(v.x); pk.h[1] = f2h(v.y); pk.h[2] = f2h(v.z); pk.h[3] = f2h(v.w);
    ((uint2*)xb)[i] = pk.u;
  }
}

// Wt[(which*768 + h*64 + c) * 768 + m] = W_{which}[h][m][c]   (B^T layout, f16)
__global__ __launch_bounds__(256) void prep_wqkv_kernel(const float* __restrict__ WQ,
                                                        const float* __restrict__ WK,
                                                        const float* __restrict__ WV,
                                                        f16* __restrict__ Wt) {
  int id = blockIdx.x * 256 + threadIdx.x;
  int R = id / DM, m = id - R * DM;
  const float* W = (R < 768) ? WQ : (R < 1536) ? WK : WV;
  int rr = (R >= 1536) ? R - 1536 : (R >= 768) ? R - 768 : R;
  int h = rr >> 6, c = rr & 63;
  Wt[id] = f2h(W[(h * DM + m) * DK + c]);
}

__global__ __launch_bounds__(256) void prep_wo_kernel(const float* __restrict__ WO,
                                                      f16* __restrict__ Wt) {
  int id = blockIdx.x * 256 + threadIdx.x;
  int d = id / DM, n = id - d * DM;
  Wt[id] = f2h(WO[n * DM + d]);
}

// V [h][b][s][64] -> Vt [h][b][d][s]  (64x64 LDS tile transpose)
__global__ __launch_bounds__(256) void transpose_v_kernel(const f16* __restrict__ V,
                                                          f16* __restrict__ Vt) {
  __shared__ __align__(16) f16 L[64 * 72];
  const int s0 = blockIdx.x * 64;
  const int hb = blockIdx.y;  // h*B+b
  const f16* Vp = V + (size_t)hb * S_ * DK;
  f16* Vtp = Vt + (size_t)hb * S_ * DK;
  const int t = threadIdx.x;
  const int sr = t >> 3, c8 = (t & 7) * 8;
  *(uint4*)&L[sr * 72 + c8] = *(const uint4*)(Vp + (size_t)(s0 + sr) * DK + c8);
  *(uint4*)&L[(sr + 32) * 72 + c8] =
      *(const uint4*)(Vp + (size_t)(s0 + sr + 32) * DK + c8);
  __syncthreads();
  union { f16 h[8]; uint4 u; } pk;
#pragma unroll
  for (int half = 0; half < 2; half++) {
    int d = (t >> 3) + half * 32;
#pragma unroll
    for (int j = 0; j < 8; j++) pk.h[j] = L[(c8 + j) * 72 + d];
    *(uint4*)(Vtp + (size_t)d * S_ + s0 + c8) = pk.u;
  }
}

// ---------------- GEMM: C[M,N] = A[M,K] * Bt[N,K]^T, K=768 ----------------
template <int MODE>
__global__ __launch_bounds__(256) void gemm_bt_kernel(const f16* __restrict__ A,
                                                      const f16* __restrict__ Bt,
                                                      float* __restrict__ Cf,
                                                      f16* __restrict__ Cq, int N) {
  constexpr int K = 768;
  __shared__ __align__(16) f16 As[128 * 40];
  __shared__ __align__(16) f16 Bs[128 * 40];
  const int t = threadIdx.x;
  const int m0 = blockIdx.y * 128, n0 = blockIdx.x * 128;
  const int lane = t & 63, wave = t >> 6;
  const int l15 = lane & 15, quad = lane >> 4;
  const int m_off = (wave & 1) * 64, n_off = (wave >> 1) * 64;
  const int srow = t >> 2, skc = (t & 3) * 8;
  const f16* Ag = A + (size_t)(m0 + srow) * K + skc;
  const f16* Bg = Bt + (size_t)(n0 + srow) * K + skc;
  f32x4 acc[4][4];
  const f32x4 z4 = {0.f, 0.f, 0.f, 0.f};
  for (int i = 0; i < 4; i++)
    for (int j = 0; j < 4; j++) acc[i][j] = z4;

  for (int kt = 0; kt < K; kt += 32) {
    uint4 a0 = *(const uint4*)(Ag + kt);
    uint4 a1 = *(const uint4*)(Ag + (size_t)64 * K + kt);
    uint4 b0 = *(const uint4*)(Bg + kt);
    uint4 b1 = *(const uint4*)(Bg + (size_t)64 * K + kt);
    __syncthreads();
    *(uint4*)&As[srow * 40 + skc] = a0;
    *(uint4*)&As[(srow + 64) * 40 + skc] = a1;
    *(uint4*)&Bs[srow * 40 + skc] = b0;
    *(uint4*)&Bs[(srow + 64) * 40 + skc] = b1;
    __syncthreads();
    f16x8 af[4], bfr[4];
#pragma unroll
    for (int i = 0; i < 4; i++)
      af[i] = *(const f16x8*)&As[(m_off + i * 16 + l15) * 40 + quad * 8];
#pragma unroll
    for (int i = 0; i < 4; i++)
      bfr[i] = *(const f16x8*)&Bs[(n_off + i * 16 + l15) * 40 + quad * 8];
#pragma unroll
    for (int mi = 0; mi < 4; mi++)
#pragma unroll
      for (int ni = 0; ni < 4; ni++)
        acc[mi][ni] = __builtin_amdgcn_mfma_f32_16x16x32_f16(af[mi], bfr[ni],
                                                             acc[mi][ni], 0, 0, 0);
  }

  if (MODE == 0) {
#pragma unroll
    for (int mi = 0; mi < 4; mi++) {
      int row = m0 + m_off + mi * 16 + quad * 4;
#pragma unroll
      for (int ni = 0; ni < 4; ni++) {
        int col = n0 + n_off + ni * 16 + l15;
#pragma unroll
        for (int r = 0; r < 4; r++) Cf[(size_t)(row + r) * N + col] = acc[mi][ni][r];
      }
    }
  } else {
#pragma unroll
    for (int mi = 0; mi < 4; mi++) {
#pragma unroll
      for (int ni = 0; ni < 4; ni++) {
        int n = n0 + n_off + ni * 16 + l15;
        int which = n / DM;
        int rr = n - which * DM;
        int h = rr >> 6, kk = rr & 63;
#pragma unroll
        for (int r = 0; r < 4; r++) {
          int m = m0 + m_off + mi * 16 + quad * 4 + r;
          int b = m >> 11, s = m & 2047;
          size_t dst = (size_t)which * ((size_t)H_ * B_ * S_ * DK) +
                       ((size_t)((h * B_ + b) * S_ + s)) * DK + kk;
          Cq[dst] = f2h(acc[mi][ni][r]);
        }
      }
    }
  }
}

// ---------------- flash attention v2 ----------------
// grid (S/64, B, H) with qb reversed (longest-first), 256 threads.
// Q/K in [h][b][s][64]; Vt in [h][b][d][s]. Output MH f16 [b][q][h*64+v].
// Computes S^T = K Q^T so softmax state is per-lane scalar (q = lane&15).
__global__ __launch_bounds__(256, 5) void flash_kernel(const f16* __restrict__ Qg,
                                                       const f16* __restrict__ Kg,
                                                       const f16* __restrict__ Vtg,
                                                       f16* __restrict__ MH) {
  const int qb = (int)gridDim.x - 1 - (int)blockIdx.x;
  const int b = blockIdx.y, h = blockIdx.z;
  const size_t base = ((size_t)(h * B_ + b) * S_) * DK;
  const f16* Qp = Qg + base;
  const f16* Kp = Kg + base;
  const f16* Vp = Vtg + base;  // [d][S]

  __shared__ __align__(16) f16 Ks[64 * 72];
  __shared__ __align__(16) f16 Vts[64 * 72];
  __shared__ __align__(16) f16 Ps[4][16 * 72];

  const int t = threadIdx.x, lane = t & 63, w = t >> 6;
  const int l15 = lane & 15, quad = lane >> 4;
  const int q0 = qb * 64;

  // Q fragments once, direct from global (lane l15 = q row, k contiguous)
  f16x8 aq[2];
  {
    const f16* qrow = Qp + (size_t)(q0 + w * 16 + l15) * DK + quad * 8;
    aq[0] = *(const f16x8*)(qrow);
    aq[1] = *(const f16x8*)(qrow + 32);
  }

  const int srow = t >> 3;       // 0..31
  const int scol = (t & 7) * 8;  // 0..56
  uint4 kreg[2], vreg[2];
  {  // prefetch tile 0
    const f16* kp = Kp + (size_t)srow * DK + scol;
    kreg[0] = *(const uint4*)(kp);
    kreg[1] = *(const uint4*)(kp + 32 * DK);
    const f16* vp = Vp + (size_t)srow * S_ + scol;
    vreg[0] = *(const uint4*)(vp);
    vreg[1] = *(const uint4*)(vp + (size_t)32 * S_);
  }

  float mrow = -1e30f, lrow = 0.f;
  f32x4 oacc[4];
  const f32x4 z4 = {0.f, 0.f, 0.f, 0.f};
  for (int i = 0; i < 4; i++) oacc[i] = z4;

  const int qg = q0 + w * 16 + l15;  // this lane's q column

  for (int kt = 0; kt <= qb; kt++) {
    __syncthreads();  // all waves done reading prev tile's LDS
    *(uint4*)&Ks[srow * 72 + scol] = kreg[0];
    *(uint4*)&Ks[(srow + 32) * 72 + scol] = kreg[1];
    *(uint4*)&Vts[srow * 72 + scol] = vreg[0];
    *(uint4*)&Vts[(srow + 32) * 72 + scol] = vreg[1];
    __syncthreads();
    if (kt < qb) {  // prefetch next tile; latency hides behind compute
      const int kv1 = (kt + 1) * 64;
      const f16* kp = Kp + (size_t)(kv1 + srow) * DK + scol;
      kreg[0] = *(const uint4*)(kp);
      kreg[1] = *(const uint4*)(kp + 32 * DK);
      const f16* vp = Vp + (size_t)srow * S_ + kv1 + scol;
      vreg[0] = *(const uint4*)(vp);
      vreg[1] = *(const uint4*)(vp + (size_t)32 * S_);
    }

    // S^T[kv][q]: rows kv = mi*16 + quad*4 + r, col q = l15
    f32x4 sa[4];
    for (int i = 0; i < 4; i++) sa[i] = z4;
#pragma unroll
    for (int kc2 = 0; kc2 < 2; kc2++) {
#pragma unroll
      for (int mi = 0; mi < 4; mi++) {
        f16x8 ak = *(const f16x8*)&Ks[(mi * 16 + l15) * 72 + kc2 * 32 + quad * 8];
        sa[mi] = __builtin_amdgcn_mfma_f32_16x16x32_f16(ak, aq[kc2], sa[mi], 0, 0, 0);
      }
    }

    const bool diag = (kt == qb);
    const int kv0 = kt * 64;
#pragma unroll
    for (int mi = 0; mi < 4; mi++) {
#pragma unroll
      for (int r = 0; r < 4; r++) {
        float s = sa[mi][r] * 0.125f;
        if (diag) {
          int kv = kv0 + mi * 16 + quad * 4 + r;
          if (kv > qg) s = -1e30f;
        }
        sa[mi][r] = s;
      }
    }

    // per-lane online softmax over this lane's q column
    float mx = -1e30f;
#pragma unroll
    for (int mi = 0; mi < 4; mi++)
#pragma unroll
      for (int r = 0; r < 4; r++) mx = fmaxf(mx, sa[mi][r]);
    mx = fmaxf(mx, __shfl_xor(mx, 16));
    mx = fmaxf(mx, __shfl_xor(mx, 32));
    float mn = fmaxf(mrow, mx);
    float alpha = __expf(mrow - mn);
    mrow = mn;
    float rs = 0.f;
#pragma unroll
    for (int mi = 0; mi < 4; mi++)
#pragma unroll
      for (int r = 0; r < 4; r++) {
        float p = __expf(sa[mi][r] - mn);
        sa[mi][r] = p;
        rs += p;
      }
    rs += __shfl_xor(rs, 16);
    rs += __shfl_xor(rs, 32);
    lrow = lrow * alpha + rs;

    // P^T -> Ps[q][kv] (A-frag layout), 4 packed b64 stores per lane
#pragma unroll
    for (int mi = 0; mi < 4; mi++) {
      union { f16 h[4]; uint2 u; } pk;
#pragma unroll
      for (int r = 0; r < 4; r++) pk.h[r] = f2h(sa[mi][r]);
      *(uint2*)&Ps[w][l15 * 72 + mi * 16 + quad * 4] = pk.u;
    }

    // rescale O rows (row q = quad*4+r) by alpha from lane quad*4+r
    float ar[4];
#pragma unroll
    for (int r = 0; r < 4; r++) ar[r] = __shfl(alpha, quad * 4 + r);
#pragma unroll
    for (int ni = 0; ni < 4; ni++)
#pragma unroll
      for (int r = 0; r < 4; r++) oacc[ni][r] *= ar[r];

    // O += P V   (A = P rows q, B = Vt rows v)
#pragma unroll
    for (int kc2 = 0; kc2 < 2; kc2++) {
      f16x8 ap = *(const f16x8*)&Ps[w][l15 * 72 + kc2 * 32 + quad * 8];
#pragma unroll
      for (int ni = 0; ni < 4; ni++) {
        f16x8 bv = *(const f16x8*)&Vts[(ni * 16 + l15) * 72 + kc2 * 32 + quad * 8];
        oacc[ni] = __builtin_amdgcn_mfma_f32_16x16x32_f16(ap, bv, oacc[ni], 0, 0, 0);
      }
    }
  }

  // normalize + write MH [b][q][h*64+v]
  float linv = 1.0f / lrow;
#pragma unroll
  for (int r = 0; r < 4; r++) {
    float ir = __shfl(linv, quad * 4 + r);
    int q = q0 + w * 16 + quad * 4 + r;
    size_t rowbase = ((size_t)b * S_ + q) * DM + h * DK;
#pragma unroll
    for (int ni = 0; ni < 4; ni++)
      MH[rowbase + ni * 16 + l15] = f2h(oacc[ni][r] * ir);
  }
}

// ---------------- launch ----------------

extern "C" void kernel_launch(void* const* d_in, const int* in_sizes, int n_in,
                              void* d_out, int out_size, void* d_ws, size_t ws_size,
                              hipStream_t stream) {
  const float* residual = (const float*)d_in[0];
  const float* WQ = (const float*)d_in[1];
  const float* WK = (const float*)d_in[2];
  const float* WV = (const float*)d_in[3];
  const float* WO = (const float*)d_in[4];
  float* out = (float*)d_out;

  char* ws = (char*)d_ws;
  size_t off = 0;
  auto alloc = [&](size_t bytes) {
    void* p = ws + off;
    off += (bytes + 255) & ~(size_t)255;
    return p;
  };
  f16* xb = (f16*)alloc((size_t)B_ * S_ * DM * 2);            // 12.6 MB (reused as Vt)
  f16* wqkv = (f16*)alloc((size_t)3 * DM * DM * 2);           // 3.5 MB
  f16* wot = (f16*)alloc((size_t)DM * DM * 2);                // 1.2 MB
  f16* qkv = (f16*)alloc((size_t)3 * H_ * B_ * S_ * DK * 2);  // 37.7 MB
  f16* mh = (f16*)alloc((size_t)B_ * S_ * DM * 2);            // 12.6 MB

  cast_x_kernel<<<(B_ * S_ * DM / 4 + 255) / 256, 256, 0, stream>>>(residual, xb,
                                                                    B_ * S_ * DM / 4);
  prep_wqkv_kernel<<<(3 * DM * DM) / 256, 256, 0, stream>>>(WQ, WK, WV, wqkv);
  prep_wo_kernel<<<(DM * DM) / 256, 256, 0, stream>>>(WO, wot);

  gemm_bt_kernel<1><<<dim3(3 * DM / 128, B_ * S_ / 128), 256, 0, stream>>>(
      xb, wqkv, nullptr, qkv, 3 * DM);

  f16* qbuf = qkv;
  f16* kbuf = qkv + (size_t)H_ * B_ * S_ * DK;
  f16* vbuf = kbuf + (size_t)H_ * B_ * S_ * DK;
  f16* vt = xb;  // xb is dead after the QKV GEMM; reuse as V^T
  transpose_v_kernel<<<dim3(S_ / 64, H_ * B_), 256, 0, stream>>>(vbuf, vt);

  flash_kernel<<<dim3(S_ / 64, B_, H_), 256, 0, stream>>>(qbuf, kbuf, vt, mh);

  gemm_bt_kernel<0><<<dim3(DM / 128, B_ * S_ / 128), 256, 0, stream>>>(mh, wot, out,
                                                                       nullptr, DM);
}

// Round 4
// 292.190 us; speedup vs baseline: 1.4660x; 1.3780x over previous
//
#include <hip/hip_runtime.h>

typedef _Float16 f16;
typedef _Float16 f16x8 __attribute__((ext_vector_type(8)));
typedef float f32x4 __attribute__((ext_vector_type(4)));

#define H_ 12
#define B_ 4
#define S_ 2048
#define DM 768
#define DK 64

__device__ __forceinline__ f16 f2h(float f) { return (f16)f; }

// ---------------- prep kernels ----------------

__global__ __launch_bounds__(256) void cast_x_kernel(const float* __restrict__ x,
                                                     f16* __restrict__ xb, int n4) {
  int i = blockIdx.x * 256 + threadIdx.x;
  if (i < n4) {
    float4 v = ((const float4*)x)[i];
    union { f16 h[4]; uint2 u; } pk;
    pk.h[0] = f2h(v.x); pk.h[1] = f2h(v.y); pk.h[2] = f2h(v.z); pk.h[3] = f2h(v.w);
    ((uint2*)xb)[i] = pk.u;
  }
}

// Wt[(which*768 + h*64 + c) * 768 + m] = W_{which}[h][m][c]   (B^T layout, f16)
__global__ __launch_bounds__(256) void prep_wqkv_kernel(const float* __restrict__ WQ,
                                                        const float* __restrict__ WK,
                                                        const float* __restrict__ WV,
                                                        f16* __restrict__ Wt) {
  int id = blockIdx.x * 256 + threadIdx.x;
  int R = id / DM, m = id - R * DM;
  const float* W = (R < 768) ? WQ : (R < 1536) ? WK : WV;
  int rr = (R >= 1536) ? R - 1536 : (R >= 768) ? R - 768 : R;
  int h = rr >> 6, c = rr & 63;
  Wt[id] = f2h(W[(h * DM + m) * DK + c]);
}

__global__ __launch_bounds__(256) void prep_wo_kernel(const float* __restrict__ WO,
                                                      f16* __restrict__ Wt) {
  int id = blockIdx.x * 256 + threadIdx.x;
  int d = id / DM, n = id - d * DM;
  Wt[id] = f2h(WO[n * DM + d]);
}

// V [h][b][s][64] -> Vt [h][b][d][s]  (64x64 LDS tile transpose)
__global__ __launch_bounds__(256) void transpose_v_kernel(const f16* __restrict__ V,
                                                          f16* __restrict__ Vt) {
  __shared__ __align__(16) f16 L[64 * 72];
  const int s0 = blockIdx.x * 64;
  const int hb = blockIdx.y;  // h*B+b
  const f16* Vp = V + (size_t)hb * S_ * DK;
  f16* Vtp = Vt + (size_t)hb * S_ * DK;
  const int t = threadIdx.x;
  const int sr = t >> 3, c8 = (t & 7) * 8;
  *(uint4*)&L[sr * 72 + c8] = *(const uint4*)(Vp + (size_t)(s0 + sr) * DK + c8);
  *(uint4*)&L[(sr + 32) * 72 + c8] =
      *(const uint4*)(Vp + (size_t)(s0 + sr + 32) * DK + c8);
  __syncthreads();
  union { f16 h[8]; uint4 u; } pk;
#pragma unroll
  for (int half = 0; half < 2; half++) {
    int d = (t >> 3) + half * 32;
#pragma unroll
    for (int j = 0; j < 8; j++) pk.h[j] = L[(c8 + j) * 72 + d];
    *(uint4*)(Vtp + (size_t)d * S_ + s0 + c8) = pk.u;
  }
}

// ---------------- GEMM: C[M,N] = A[M,K] * Bt[N,K]^T, K=768 ----------------
template <int MODE>
__global__ __launch_bounds__(256) void gemm_bt_kernel(const f16* __restrict__ A,
                                                      const f16* __restrict__ Bt,
                                                      float* __restrict__ Cf,
                                                      f16* __restrict__ Cq, int N) {
  constexpr int K = 768;
  __shared__ __align__(16) f16 As[128 * 40];
  __shared__ __align__(16) f16 Bs[128 * 40];
  const int t = threadIdx.x;
  const int m0 = blockIdx.y * 128, n0 = blockIdx.x * 128;
  const int lane = t & 63, wave = t >> 6;
  const int l15 = lane & 15, quad = lane >> 4;
  const int m_off = (wave & 1) * 64, n_off = (wave >> 1) * 64;
  const int srow = t >> 2, skc = (t & 3) * 8;
  const f16* Ag = A + (size_t)(m0 + srow) * K + skc;
  const f16* Bg = Bt + (size_t)(n0 + srow) * K + skc;
  f32x4 acc[4][4];
  const f32x4 z4 = {0.f, 0.f, 0.f, 0.f};
  for (int i = 0; i < 4; i++)
    for (int j = 0; j < 4; j++) acc[i][j] = z4;

  for (int kt = 0; kt < K; kt += 32) {
    uint4 a0 = *(const uint4*)(Ag + kt);
    uint4 a1 = *(const uint4*)(Ag + (size_t)64 * K + kt);
    uint4 b0 = *(const uint4*)(Bg + kt);
    uint4 b1 = *(const uint4*)(Bg + (size_t)64 * K + kt);
    __syncthreads();
    *(uint4*)&As[srow * 40 + skc] = a0;
    *(uint4*)&As[(srow + 64) * 40 + skc] = a1;
    *(uint4*)&Bs[srow * 40 + skc] = b0;
    *(uint4*)&Bs[(srow + 64) * 40 + skc] = b1;
    __syncthreads();
    f16x8 af[4], bfr[4];
#pragma unroll
    for (int i = 0; i < 4; i++)
      af[i] = *(const f16x8*)&As[(m_off + i * 16 + l15) * 40 + quad * 8];
#pragma unroll
    for (int i = 0; i < 4; i++)
      bfr[i] = *(const f16x8*)&Bs[(n_off + i * 16 + l15) * 40 + quad * 8];
#pragma unroll
    for (int mi = 0; mi < 4; mi++)
#pragma unroll
      for (int ni = 0; ni < 4; ni++)
        acc[mi][ni] = __builtin_amdgcn_mfma_f32_16x16x32_f16(af[mi], bfr[ni],
                                                             acc[mi][ni], 0, 0, 0);
  }

  if (MODE == 0) {
#pragma unroll
    for (int mi = 0; mi < 4; mi++) {
      int row = m0 + m_off + mi * 16 + quad * 4;
#pragma unroll
      for (int ni = 0; ni < 4; ni++) {
        int col = n0 + n_off + ni * 16 + l15;
#pragma unroll
        for (int r = 0; r < 4; r++) Cf[(size_t)(row + r) * N + col] = acc[mi][ni][r];
      }
    }
  } else {
#pragma unroll
    for (int mi = 0; mi < 4; mi++) {
#pragma unroll
      for (int ni = 0; ni < 4; ni++) {
        int n = n0 + n_off + ni * 16 + l15;
        int which = n / DM;
        int rr = n - which * DM;
        int h = rr >> 6, kk = rr & 63;
#pragma unroll
        for (int r = 0; r < 4; r++) {
          int m = m0 + m_off + mi * 16 + quad * 4 + r;
          int b = m >> 11, s = m & 2047;
          size_t dst = (size_t)which * ((size_t)H_ * B_ * S_ * DK) +
                       ((size_t)((h * B_ + b) * S_ + s)) * DK + kk;
          Cq[dst] = f2h(acc[mi][ni][r]);
        }
      }
    }
  }
}

// ---------------- flash attention v3: barrier-free kv-split ----------------
// grid (S/64, B, H), qb reversed. 256 threads = 4 waves.
// Wave w handles kv-tiles kt = w, w+4, ... with private online-softmax state
// over ALL 64 q of the block; 2-barrier merge epilogue combines the 4 partials.
// Q/K in [h][b][s][64]; Vt in [h][b][d][s]. Output MH f16 [b][q][h*64+v].
__global__ __launch_bounds__(256, 2) void flash_kernel(const f16* __restrict__ Qg,
                                                       const f16* __restrict__ Kg,
                                                       const f16* __restrict__ Vtg,
                                                       f16* __restrict__ MH) {
  const int qb = (int)gridDim.x - 1 - (int)blockIdx.x;
  const int b = blockIdx.y, h = blockIdx.z;
  const size_t base = ((size_t)(h * B_ + b) * S_) * DK;
  const f16* Qp = Qg + base;
  const f16* Kp = Kg + base;
  const f16* Vp = Vtg + base;  // [d][S_]

  __shared__ __align__(16) f16 Om[4][64][72];  // 36.9 KB partial-O exchange
  __shared__ __align__(16) f16 Ps[4][16 * 72]; // 9.2 KB per-wave P tile
  __shared__ float Ms[4][64], Ls[4][64];       // 2 KB

  const int t = threadIdx.x, lane = t & 63, w = t >> 6;
  const int l15 = lane & 15, quad = lane >> 4;
  const int q0 = qb * 64;

  // Q A-operand-shaped fragments for all 4 q-groups, direct from global
  f16x8 aq[4][2];
#pragma unroll
  for (int qg = 0; qg < 4; qg++) {
    const f16* qrow = Qp + (size_t)(q0 + qg * 16 + l15) * DK + quad * 8;
    aq[qg][0] = *(const f16x8*)(qrow);
    aq[qg][1] = *(const f16x8*)(qrow + 32);
  }

  float m_s[4] = {-1e30f, -1e30f, -1e30f, -1e30f};
  float l_s[4] = {0.f, 0.f, 0.f, 0.f};
  f32x4 oacc[4][4];
  const f32x4 z4 = {0.f, 0.f, 0.f, 0.f};
#pragma unroll
  for (int qg = 0; qg < 4; qg++)
#pragma unroll
    for (int ni = 0; ni < 4; ni++) oacc[qg][ni] = z4;

  for (int kt = w; kt <= qb; kt += 4) {
    const int kv0 = kt * 64;
    // K/V fragments straight from global in MFMA operand order
    f16x8 kf[4][2], vf[4][2];
#pragma unroll
    for (int mi = 0; mi < 4; mi++) {
      const f16* kp = Kp + (size_t)(kv0 + mi * 16 + l15) * DK + quad * 8;
      kf[mi][0] = *(const f16x8*)(kp);
      kf[mi][1] = *(const f16x8*)(kp + 32);
    }
#pragma unroll
    for (int ni = 0; ni < 4; ni++) {
      const f16* vp = Vp + (size_t)(ni * 16 + l15) * S_ + kv0 + quad * 8;
      vf[ni][0] = *(const f16x8*)(vp);
      vf[ni][1] = *(const f16x8*)(vp + 32);
    }
    const bool diag = (kt == qb);

#pragma unroll
    for (int qg = 0; qg < 4; qg++) {
      // S^T tile: rows kv = mi*16+quad*4+r, col q = qg*16+l15
      f32x4 sa[4];
#pragma unroll
      for (int mi = 0; mi < 4; mi++)
        sa[mi] = __builtin_amdgcn_mfma_f32_16x16x32_f16(kf[mi][0], aq[qg][0], z4, 0, 0, 0);
#pragma unroll
      for (int mi = 0; mi < 4; mi++)
        sa[mi] = __builtin_amdgcn_mfma_f32_16x16x32_f16(kf[mi][1], aq[qg][1], sa[mi], 0, 0, 0);

      if (diag) {  // wave-uniform branch; only diagonal tile masks
        int qgl = q0 + qg * 16 + l15;
#pragma unroll
        for (int mi = 0; mi < 4; mi++)
#pragma unroll
          for (int r = 0; r < 4; r++)
            if (kv0 + mi * 16 + quad * 4 + r > qgl) sa[mi][r] = -1e30f;
      }

      // per-lane online softmax (q = l15 column); max over raw, scale once
      float mx = fmaxf(fmaxf(fmaxf(sa[0][0], sa[0][1]), fmaxf(sa[0][2], sa[0][3])),
                       fmaxf(fmaxf(sa[1][0], sa[1][1]), fmaxf(sa[1][2], sa[1][3])));
      float mx2 = fmaxf(fmaxf(fmaxf(sa[2][0], sa[2][1]), fmaxf(sa[2][2], sa[2][3])),
                        fmaxf(fmaxf(sa[3][0], sa[3][1]), fmaxf(sa[3][2], sa[3][3])));
      mx = fmaxf(mx, mx2);
      mx = fmaxf(mx, __shfl_xor(mx, 16));
      mx = fmaxf(mx, __shfl_xor(mx, 32));
      float mn = fmaxf(m_s[qg], 0.125f * mx);
      float alpha = __expf(m_s[qg] - mn);
      m_s[qg] = mn;
      float rs = 0.f;
#pragma unroll
      for (int mi = 0; mi < 4; mi++)
#pragma unroll
        for (int r = 0; r < 4; r++) {
          float p = __expf(fmaf(sa[mi][r], 0.125f, -mn));
          sa[mi][r] = p;
          rs += p;
        }
      rs += __shfl_xor(rs, 16);
      rs += __shfl_xor(rs, 32);
      l_s[qg] = l_s[qg] * alpha + rs;

      // P^T -> per-wave LDS in A-frag order (no barrier: private buffer)
#pragma unroll
      for (int mi = 0; mi < 4; mi++) {
        union { f16 h[4]; uint2 u; } pk;
#pragma unroll
        for (int r = 0; r < 4; r++) pk.h[r] = f2h(sa[mi][r]);
        *(uint2*)&Ps[w][l15 * 72 + mi * 16 + quad * 4] = pk.u;
      }

      // rescale O rows (row q = quad*4+r gets alpha from lane quad*4+r)
      float ar[4];
#pragma unroll
      for (int r = 0; r < 4; r++) ar[r] = __shfl(alpha, quad * 4 + r);
#pragma unroll
      for (int ni = 0; ni < 4; ni++)
#pragma unroll
        for (int r = 0; r < 4; r++) oacc[qg][ni][r] *= ar[r];

      // O += P V
#pragma unroll
      for (int kc2 = 0; kc2 < 2; kc2++) {
        f16x8 ap = *(const f16x8*)&Ps[w][l15 * 72 + kc2 * 32 + quad * 8];
#pragma unroll
        for (int ni = 0; ni < 4; ni++)
          oacc[qg][ni] = __builtin_amdgcn_mfma_f32_16x16x32_f16(ap, vf[ni][kc2],
                                                               oacc[qg][ni], 0, 0, 0);
      }
    }
  }

  // ---- merge epilogue (2 barriers per block) ----
  if (quad == 0) {
#pragma unroll
    for (int qg = 0; qg < 4; qg++) {
      Ms[w][qg * 16 + l15] = m_s[qg];
      Ls[w][qg * 16 + l15] = l_s[qg];
    }
  }
  __syncthreads();

  // this wave's rescale factor exp(m_w - M) per q, then stash scaled O (f16)
#pragma unroll
  for (int qg = 0; qg < 4; qg++) {
    int qi = qg * 16 + l15;
    float M = fmaxf(fmaxf(Ms[0][qi], Ms[1][qi]), fmaxf(Ms[2][qi], Ms[3][qi]));
    float scq = __expf(m_s[qg] - M);
    float sc[4];
#pragma unroll
    for (int r = 0; r < 4; r++) sc[r] = __shfl(scq, quad * 4 + r);
#pragma unroll
    for (int ni = 0; ni < 4; ni++)
#pragma unroll
      for (int r = 0; r < 4; r++)
        Om[w][qg * 16 + quad * 4 + r][ni * 16 + l15] = f2h(oacc[qg][ni][r] * sc[r]);
  }
  __syncthreads();

  // merge: wave w handles q-rows w*16..w*16+15; lane covers v = quad*16..+15
  {
    int ql = w * 16 + l15;
    float M = fmaxf(fmaxf(Ms[0][ql], Ms[1][ql]), fmaxf(Ms[2][ql], Ms[3][ql]));
    float L = Ls[0][ql] * __expf(Ms[0][ql] - M) + Ls[1][ql] * __expf(Ms[1][ql] - M) +
              Ls[2][ql] * __expf(Ms[2][ql] - M) + Ls[3][ql] * __expf(Ms[3][ql] - M);
    float linv = 1.0f / L;
    float acc[16];
#pragma unroll
    for (int j = 0; j < 16; j++) acc[j] = 0.f;
#pragma unroll
    for (int wp = 0; wp < 4; wp++) {
      f16x8 o0 = *(const f16x8*)&Om[wp][ql][quad * 16];
      f16x8 o1 = *(const f16x8*)&Om[wp][ql][quad * 16 + 8];
#pragma unroll
      for (int j = 0; j < 8; j++) {
        acc[j] += (float)o0[j];
        acc[8 + j] += (float)o1[j];
      }
    }
    union { f16 h[16]; uint4 u[2]; } pk;
#pragma unroll
    for (int j = 0; j < 16; j++) pk.h[j] = f2h(acc[j] * linv);
    f16* dst = MH + ((size_t)b * S_ + q0 + ql) * DM + h * DK + quad * 16;
    *(uint4*)(dst) = pk.u[0];
    *(uint4*)(dst + 8) = pk.u[1];
  }
}

// ---------------- launch ----------------

extern "C" void kernel_launch(void* const* d_in, const int* in_sizes, int n_in,
                              void* d_out, int out_size, void* d_ws, size_t ws_size,
                              hipStream_t stream) {
  const float* residual = (const float*)d_in[0];
  const float* WQ = (const float*)d_in[1];
  const float* WK = (const float*)d_in[2];
  const float* WV = (const float*)d_in[3];
  const float* WO = (const float*)d_in[4];
  float* out = (float*)d_out;

  char* ws = (char*)d_ws;
  size_t off = 0;
  auto alloc = [&](size_t bytes) {
    void* p = ws + off;
    off += (bytes + 255) & ~(size_t)255;
    return p;
  };
  f16* xb = (f16*)alloc((size_t)B_ * S_ * DM * 2);            // 12.6 MB (reused as Vt)
  f16* wqkv = (f16*)alloc((size_t)3 * DM * DM * 2);           // 3.5 MB
  f16* wot = (f16*)alloc((size_t)DM * DM * 2);                // 1.2 MB
  f16* qkv = (f16*)alloc((size_t)3 * H_ * B_ * S_ * DK * 2);  // 37.7 MB
  f16* mh = (f16*)alloc((size_t)B_ * S_ * DM * 2);            // 12.6 MB

  cast_x_kernel<<<(B_ * S_ * DM / 4 + 255) / 256, 256, 0, stream>>>(residual, xb,
                                                                    B_ * S_ * DM / 4);
  prep_wqkv_kernel<<<(3 * DM * DM) / 256, 256, 0, stream>>>(WQ, WK, WV, wqkv);
  prep_wo_kernel<<<(DM * DM) / 256, 256, 0, stream>>>(WO, wot);

  gemm_bt_kernel<1><<<dim3(3 * DM / 128, B_ * S_ / 128), 256, 0, stream>>>(
      xb, wqkv, nullptr, qkv, 3 * DM);

  f16* qbuf = qkv;
  f16* kbuf = qkv + (size_t)H_ * B_ * S_ * DK;
  f16* vbuf = kbuf + (size_t)H_ * B_ * S_ * DK;
  f16* vt = xb;  // xb dead after QKV GEMM; reuse as V^T
  transpose_v_kernel<<<dim3(S_ / 64, H_ * B_), 256, 0, stream>>>(vbuf, vt);

  flash_kernel<<<dim3(S_ / 64, B_, H_), 256, 0, stream>>>(qbuf, kbuf, vt, mh);

  gemm_bt_kernel<0><<<dim3(DM / 128, B_ * S_ / 128), 256, 0, stream>>>(mh, wot, out,
                                                                       nullptr, DM);
}

// Round 5
// 283.445 us; speedup vs baseline: 1.5112x; 1.0309x over previous
//
#include <hip/hip_runtime.h>

typedef _Float16 f16;
typedef _Float16 f16x8 __attribute__((ext_vector_type(8)));
typedef float f32x4 __attribute__((ext_vector_type(4)));

#define H_ 12
#define B_ 4
#define S_ 2048
#define DM 768
#define DK 64
#define HBSD ((size_t)H_ * B_ * S_ * DK)

__device__ __forceinline__ f16 f2h(float f) { return (f16)f; }

// async global->LDS, 16B per lane. LDS dest must be wave-uniform base + lane*16.
__device__ __forceinline__ void gl_lds16(const f16* g, f16* l) {
  __builtin_amdgcn_global_load_lds(
      (const __attribute__((address_space(1))) void*)g,
      (__attribute__((address_space(3))) void*)l, 16, 0, 0);
}

// ---------------- prep kernels ----------------

__global__ __launch_bounds__(256) void cast_x_kernel(const float* __restrict__ x,
                                                     f16* __restrict__ xb, int n4) {
  int i = blockIdx.x * 256 + threadIdx.x;
  if (i < n4) {
    float4 v = ((const float4*)x)[i];
    union { f16 h[4]; uint2 u; } pk;
    pk.h[0] = f2h(v.x); pk.h[1] = f2h(v.y); pk.h[2] = f2h(v.z); pk.h[3] = f2h(v.w);
    ((uint2*)xb)[i] = pk.u;
  }
}

// W_{which}[h][m][c] -> Wt[(which*768 + h*64 + c)][m]  (coalesced LDS transpose)
__global__ __launch_bounds__(256) void tcast_qkv_kernel(const float* __restrict__ WQ,
                                                        const float* __restrict__ WK,
                                                        const float* __restrict__ WV,
                                                        f16* __restrict__ Wt) {
  __shared__ float L[64][65];
  const int m0 = blockIdx.x * 64, which = blockIdx.y, h = blockIdx.z;
  const float* in = (which == 0 ? WQ : which == 1 ? WK : WV) + (size_t)h * DM * DK;
  const int t = threadIdx.x;
  const int lr = t >> 2, lc = (t & 3) * 16;
  const float* ip = in + (size_t)(m0 + lr) * DK + lc;
#pragma unroll
  for (int i = 0; i < 4; i++) {
    float4 v = *(const float4*)(ip + i * 4);
    L[lr][lc + i * 4 + 0] = v.x;
    L[lr][lc + i * 4 + 1] = v.y;
    L[lr][lc + i * 4 + 2] = v.z;
    L[lr][lc + i * 4 + 3] = v.w;
  }
  __syncthreads();
  const int oc = t >> 2, om = (t & 3) * 16;
  union { f16 hh[16]; uint4 u[2]; } pk;
#pragma unroll
  for (int jx = 0; jx < 16; jx++) pk.hh[jx] = f2h(L[om + jx][oc]);
  f16* op = Wt + ((size_t)which * DM + h * DK + oc) * DM + m0 + om;
  *(uint4*)op = pk.u[0];
  *(uint4*)(op + 8) = pk.u[1];
}

// WO[n][d] -> Wot[d][n]
__global__ __launch_bounds__(256) void tcast_wo_kernel(const float* __restrict__ WO,
                                                       f16* __restrict__ Wt) {
  __shared__ float L[64][65];
  const int n0 = blockIdx.x * 64, d0 = blockIdx.y * 64;
  const int t = threadIdx.x;
  const int lr = t >> 2, lc = (t & 3) * 16;
  const float* ip = WO + (size_t)(n0 + lr) * DM + d0 + lc;
#pragma unroll
  for (int i = 0; i < 4; i++) {
    float4 v = *(const float4*)(ip + i * 4);
    L[lr][lc + i * 4 + 0] = v.x;
    L[lr][lc + i * 4 + 1] = v.y;
    L[lr][lc + i * 4 + 2] = v.z;
    L[lr][lc + i * 4 + 3] = v.w;
  }
  __syncthreads();
  const int oc = t >> 2, om = (t & 3) * 16;
  union { f16 hh[16]; uint4 u[2]; } pk;
#pragma unroll
  for (int jx = 0; jx < 16; jx++) pk.hh[jx] = f2h(L[om + jx][oc]);
  f16* op = Wt + (size_t)(d0 + oc) * DM + n0 + om;
  *(uint4*)op = pk.u[0];
  *(uint4*)(op + 8) = pk.u[1];
}

// ---------------- GEMM (m97 structure): C[M,N] = A[M,K] * Bt[N,K]^T ----------------
// MODE 0: fp32 out row-major [M,N].
// MODE 1: f16 out; which=n/768: 0,1 -> scatter to qk [h][b][s][64];
//                               2   -> write V TRANSPOSED to Vt [h][b][d][s].
template <int MODE>
__global__ __launch_bounds__(256) void gemm_bt_kernel(const f16* __restrict__ A,
                                                      const f16* __restrict__ Bt,
                                                      float* __restrict__ Cf,
                                                      f16* __restrict__ Cq,
                                                      f16* __restrict__ Vt, int N) {
  constexpr int K = 768;
  __shared__ __align__(16) f16 As[128 * 32];  // unpadded: global_load_lds lane order
  __shared__ __align__(16) f16 Bs[128 * 32];
  const int t = threadIdx.x;
  const int m0 = blockIdx.y * 128, n0 = blockIdx.x * 128;
  const int lane = t & 63, wave = t >> 6;
  const int l15 = lane & 15, quad = lane >> 4;
  const int m_off = (wave & 1) * 64, n_off = (wave >> 1) * 64;
  // staging chunks: c = t (rows 0..63) and c+256 (rows 64..127); row=c>>2, ko=(c&3)*8
  const int r0 = t >> 2, ko = (t & 3) * 8;
  const f16* Ag0 = A + (size_t)(m0 + r0) * K + ko;
  const f16* Ag1 = A + (size_t)(m0 + r0 + 64) * K + ko;
  const f16* Bg0 = Bt + (size_t)(n0 + r0) * K + ko;
  const f16* Bg1 = Bt + (size_t)(n0 + r0 + 64) * K + ko;
  f16* lA0 = &As[t * 8];
  f16* lA1 = &As[(t + 256) * 8];
  f16* lB0 = &Bs[t * 8];
  f16* lB1 = &Bs[(t + 256) * 8];

  f32x4 acc[4][4];
  const f32x4 z4 = {0.f, 0.f, 0.f, 0.f};
  for (int i = 0; i < 4; i++)
    for (int j = 0; j < 4; j++) acc[i][j] = z4;

  for (int kt = 0; kt < K; kt += 32) {
    __syncthreads();  // prev iter's LDS reads done
    gl_lds16(Ag0 + kt, lA0);
    gl_lds16(Ag1 + kt, lA1);
    gl_lds16(Bg0 + kt, lB0);
    gl_lds16(Bg1 + kt, lB1);
    __syncthreads();  // barrier drains vmcnt -> LDS populated
    f16x8 af[4], bfr[4];
#pragma unroll
    for (int i = 0; i < 4; i++)
      af[i] = *(const f16x8*)&As[(m_off + i * 16 + l15) * 32 + quad * 8];
#pragma unroll
    for (int i = 0; i < 4; i++)
      bfr[i] = *(const f16x8*)&Bs[(n_off + i * 16 + l15) * 32 + quad * 8];
#pragma unroll
    for (int mi = 0; mi < 4; mi++)
#pragma unroll
      for (int ni = 0; ni < 4; ni++)
        acc[mi][ni] = __builtin_amdgcn_mfma_f32_16x16x32_f16(af[mi], bfr[ni],
                                                             acc[mi][ni], 0, 0, 0);
  }

  if (MODE == 0) {
#pragma unroll
    for (int mi = 0; mi < 4; mi++) {
      int row = m0 + m_off + mi * 16 + quad * 4;
#pragma unroll
      for (int ni = 0; ni < 4; ni++) {
        int col = n0 + n_off + ni * 16 + l15;
#pragma unroll
        for (int r = 0; r < 4; r++) Cf[(size_t)(row + r) * N + col] = acc[mi][ni][r];
      }
    }
  } else {
#pragma unroll
    for (int mi = 0; mi < 4; mi++) {
      int srow = m0 + m_off + mi * 16 + quad * 4;
      int bb = srow >> 11, ss = srow & 2047;
#pragma unroll
      for (int ni = 0; ni < 4; ni++) {
        int n = n0 + n_off + ni * 16 + l15;
        int which = n / DM;
        int rr = n - which * DM;
        int h = rr >> 6, kk = rr & 63;
        if (which < 2) {  // Q,K -> [h][b][s][64]
#pragma unroll
          for (int r = 0; r < 4; r++) {
            size_t dst = (size_t)which * HBSD +
                         ((size_t)((h * B_ + bb) * S_) + ss + r) * DK + kk;
            Cq[dst] = f2h(acc[mi][ni][r]);
          }
        } else {  // V -> Vt [h][b][d][s], 4 consecutive s pack to b64
          union { f16 hh[4]; uint2 u; } pk;
#pragma unroll
          for (int r = 0; r < 4; r++) pk.hh[r] = f2h(acc[mi][ni][r]);
          *(uint2*)&Vt[((size_t)(h * B_ + bb) * DK + kk) * S_ + ss] = pk.u;
        }
      }
    }
  }
}

// ---------------- flash attention v4: barrier-free, wave-owns-half-q-tile ----------
// 384 blocks x 4 waves. Half-job hj in [0,3072): qb = 31-hj/96, hb=(hj%96)>>1,
// half=hj&1 (32 q rows). Wave g=blk*4+w runs jobs {g, 3071-g} -> exactly 33 kv-tiles
// per wave (perfect balance). No __syncthreads anywhere; P via per-wave LDS slice.
__global__ __launch_bounds__(256)
__attribute__((amdgpu_waves_per_eu(2, 3)))
void flash_kernel(const f16* __restrict__ Qg, const f16* __restrict__ Kg,
                  const f16* __restrict__ Vtg, f16* __restrict__ MH) {
  __shared__ __align__(16) f16 Ps[4][16 * 72];
  const int t = threadIdx.x, lane = t & 63, w = t >> 6;
  const int l15 = lane & 15, quad = lane >> 4;
  const int j0 = blockIdx.x * 4 + w;  // 0..1535
  const f32x4 z4 = {0.f, 0.f, 0.f, 0.f};

  for (int jj = 0; jj < 2; jj++) {
    const int hj = jj ? (3071 - j0) : j0;
    const int a = hj / 96;
    const int qb = 31 - a;
    const int rem = hj - a * 96;
    const int hb = rem >> 1, half = rem & 1;
    const int h = hb >> 2, b = hb & 3;
    const size_t base = (size_t)hb * S_ * DK;
    const f16* Qp = Qg + base;
    const f16* Kp = Kg + base;
    const f16* Vp = Vtg + base;  // [d][S_]
    const int q0 = qb * 64 + half * 32;

    // Q fragments (32 q rows = 2 groups), direct from global
    f16x8 aq[2][2];
#pragma unroll
    for (int qg = 0; qg < 2; qg++) {
      const f16* qrow = Qp + (size_t)(q0 + qg * 16 + l15) * DK + quad * 8;
      aq[qg][0] = *(const f16x8*)(qrow);
      aq[qg][1] = *(const f16x8*)(qrow + 32);
    }

    float m_s[2] = {-1e30f, -1e30f};
    float l_s[2] = {0.f, 0.f};
    f32x4 oacc[2][4];
#pragma unroll
    for (int qg = 0; qg < 2; qg++)
#pragma unroll
      for (int ni = 0; ni < 4; ni++) oacc[qg][ni] = z4;

    for (int kt = 0; kt <= qb; kt++) {
      const int kv0 = kt * 64;
      f16x8 kf[4][2], vf[4][2];
#pragma unroll
      for (int mi = 0; mi < 4; mi++) {
        const f16* kp = Kp + (size_t)(kv0 + mi * 16 + l15) * DK + quad * 8;
        kf[mi][0] = *(const f16x8*)(kp);
        kf[mi][1] = *(const f16x8*)(kp + 32);
      }
#pragma unroll
      for (int ni = 0; ni < 4; ni++) {
        const f16* vp = Vp + (size_t)(ni * 16 + l15) * S_ + kv0 + quad * 8;
        vf[ni][0] = *(const f16x8*)(vp);
        vf[ni][1] = *(const f16x8*)(vp + 32);
      }
      const bool diag = (kt == qb);

#pragma unroll
      for (int qg = 0; qg < 2; qg++) {
        // S^T tile: rows kv = mi*16+quad*4+r, col q = q0+qg*16+l15
        f32x4 sa[4];
#pragma unroll
        for (int mi = 0; mi < 4; mi++)
          sa[mi] = __builtin_amdgcn_mfma_f32_16x16x32_f16(kf[mi][0], aq[qg][0], z4,
                                                          0, 0, 0);
#pragma unroll
        for (int mi = 0; mi < 4; mi++)
          sa[mi] = __builtin_amdgcn_mfma_f32_16x16x32_f16(kf[mi][1], aq[qg][1],
                                                          sa[mi], 0, 0, 0);

        if (diag) {
          int qgl = q0 + qg * 16 + l15;
#pragma unroll
          for (int mi = 0; mi < 4; mi++)
#pragma unroll
            for (int r = 0; r < 4; r++)
              if (kv0 + mi * 16 + quad * 4 + r > qgl) sa[mi][r] = -1e30f;
        }

        // per-lane online softmax (this lane's q column); reduce over quad dim
        float mx = fmaxf(fmaxf(fmaxf(sa[0][0], sa[0][1]), fmaxf(sa[0][2], sa[0][3])),
                         fmaxf(fmaxf(sa[1][0], sa[1][1]), fmaxf(sa[1][2], sa[1][3])));
        float mx2 = fmaxf(fmaxf(fmaxf(sa[2][0], sa[2][1]), fmaxf(sa[2][2], sa[2][3])),
                          fmaxf(fmaxf(sa[3][0], sa[3][1]), fmaxf(sa[3][2], sa[3][3])));
        mx = fmaxf(mx, mx2);
        mx = fmaxf(mx, __shfl_xor(mx, 16));
        mx = fmaxf(mx, __shfl_xor(mx, 32));
        float mn = fmaxf(m_s[qg], 0.125f * mx);
        float alpha = __expf(m_s[qg] - mn);
        m_s[qg] = mn;
        float rs = 0.f;
#pragma unroll
        for (int mi = 0; mi < 4; mi++)
#pragma unroll
          for (int r = 0; r < 4; r++) {
            float p = __expf(fmaf(sa[mi][r], 0.125f, -mn));
            sa[mi][r] = p;
            rs += p;
          }
        rs += __shfl_xor(rs, 16);
        rs += __shfl_xor(rs, 32);
        l_s[qg] = l_s[qg] * alpha + rs;

        // P^T -> per-wave LDS slice in A-frag order (no barrier needed)
#pragma unroll
        for (int mi = 0; mi < 4; mi++) {
          union { f16 hh[4]; uint2 u; } pk;
#pragma unroll
          for (int r = 0; r < 4; r++) pk.hh[r] = f2h(sa[mi][r]);
          *(uint2*)&Ps[w][l15 * 72 + mi * 16 + quad * 4] = pk.u;
        }

        // rescale O rows (row q = quad*4+r takes alpha from lane quad*4+r)
        float ar[4];
#pragma unroll
        for (int r = 0; r < 4; r++) ar[r] = __shfl(alpha, quad * 4 + r);
#pragma unroll
        for (int ni = 0; ni < 4; ni++)
#pragma unroll
          for (int r = 0; r < 4; r++) oacc[qg][ni][r] *= ar[r];

        // O += P V
#pragma unroll
        for (int kc2 = 0; kc2 < 2; kc2++) {
          f16x8 ap = *(const f16x8*)&Ps[w][l15 * 72 + kc2 * 32 + quad * 8];
#pragma unroll
          for (int ni = 0; ni < 4; ni++)
            oacc[qg][ni] = __builtin_amdgcn_mfma_f32_16x16x32_f16(
                ap, vf[ni][kc2], oacc[qg][ni], 0, 0, 0);
        }
      }
    }

    // epilogue: normalize + write MH [b][q][h*64+v]
#pragma unroll
    for (int qg = 0; qg < 2; qg++) {
      float linv = 1.0f / l_s[qg];
#pragma unroll
      for (int r = 0; r < 4; r++) {
        float ir = __shfl(linv, quad * 4 + r);
        int q = q0 + qg * 16 + quad * 4 + r;
        size_t rowbase = ((size_t)b * S_ + q) * DM + h * DK;
#pragma unroll
        for (int ni = 0; ni < 4; ni++)
          MH[rowbase + ni * 16 + l15] = f2h(oacc[qg][ni][r] * ir);
      }
    }
  }
}

// ---------------- launch ----------------

extern "C" void kernel_launch(void* const* d_in, const int* in_sizes, int n_in,
                              void* d_out, int out_size, void* d_ws, size_t ws_size,
                              hipStream_t stream) {
  const float* residual = (const float*)d_in[0];
  const float* WQ = (const float*)d_in[1];
  const float* WK = (const float*)d_in[2];
  const float* WV = (const float*)d_in[3];
  const float* WO = (const float*)d_in[4];
  float* out = (float*)d_out;

  char* ws = (char*)d_ws;
  size_t off = 0;
  auto alloc = [&](size_t bytes) {
    void* p = ws + off;
    off += (bytes + 255) & ~(size_t)255;
    return p;
  };
  f16* xb = (f16*)alloc((size_t)B_ * S_ * DM * 2);   // 12.6 MB
  f16* wqkv = (f16*)alloc((size_t)3 * DM * DM * 2);  // 3.5 MB
  f16* wot = (f16*)alloc((size_t)DM * DM * 2);       // 1.2 MB
  f16* qk = (f16*)alloc(2 * HBSD * 2);               // 25.2 MB (Q,K)
  f16* vt = (f16*)alloc(HBSD * 2);                   // 12.6 MB (V^T)
  f16* mh = (f16*)alloc((size_t)B_ * S_ * DM * 2);   // 12.6 MB

  cast_x_kernel<<<(B_ * S_ * DM / 4 + 255) / 256, 256, 0, stream>>>(residual, xb,
                                                                    B_ * S_ * DM / 4);
  tcast_qkv_kernel<<<dim3(DM / 64, 3, H_), 256, 0, stream>>>(WQ, WK, WV, wqkv);
  tcast_wo_kernel<<<dim3(DM / 64, DM / 64), 256, 0, stream>>>(WO, wot);

  gemm_bt_kernel<1><<<dim3(3 * DM / 128, B_ * S_ / 128), 256, 0, stream>>>(
      xb, wqkv, nullptr, qk, vt, 3 * DM);

  flash_kernel<<<384, 256, 0, stream>>>(qk, qk + HBSD, vt, mh);

  gemm_bt_kernel<0><<<dim3(DM / 128, B_ * S_ / 128), 256, 0, stream>>>(
      mh, wot, out, nullptr, nullptr, DM);
}

// Round 6
// 275.355 us; speedup vs baseline: 1.5556x; 1.0294x over previous
//
#include <hip/hip_runtime.h>

typedef _Float16 f16;
typedef _Float16 f16x8 __attribute__((ext_vector_type(8)));
typedef float f32x4 __attribute__((ext_vector_type(4)));

#define H_ 12
#define B_ 4
#define S_ 2048
#define DM 768
#define DK 64
#define HBSD ((size_t)H_ * B_ * S_ * DK)

__device__ __forceinline__ f16 f2h(float f) { return (f16)f; }

// async global->LDS, 16B per lane. LDS dest must be wave-uniform base + lane*16.
__device__ __forceinline__ void gl_lds16(const f16* g, f16* l) {
  __builtin_amdgcn_global_load_lds(
      (const __attribute__((address_space(1))) void*)g,
      (__attribute__((address_space(3))) void*)l, 16, 0, 0);
}

// ---------------- prep kernels ----------------

__global__ __launch_bounds__(256) void cast_x_kernel(const float* __restrict__ x,
                                                     f16* __restrict__ xb, int n4) {
  int i = blockIdx.x * 256 + threadIdx.x;
  if (i < n4) {
    float4 v = ((const float4*)x)[i];
    union { f16 h[4]; uint2 u; } pk;
    pk.h[0] = f2h(v.x); pk.h[1] = f2h(v.y); pk.h[2] = f2h(v.z); pk.h[3] = f2h(v.w);
    ((uint2*)xb)[i] = pk.u;
  }
}

// W_{which}[h][m][c] -> Wt[(which*768 + h*64 + c)][m]  (coalesced LDS transpose)
__global__ __launch_bounds__(256) void tcast_qkv_kernel(const float* __restrict__ WQ,
                                                        const float* __restrict__ WK,
                                                        const float* __restrict__ WV,
                                                        f16* __restrict__ Wt) {
  __shared__ float L[64][65];
  const int m0 = blockIdx.x * 64, which = blockIdx.y, h = blockIdx.z;
  const float* in = (which == 0 ? WQ : which == 1 ? WK : WV) + (size_t)h * DM * DK;
  const int t = threadIdx.x;
  const int lr = t >> 2, lc = (t & 3) * 16;
  const float* ip = in + (size_t)(m0 + lr) * DK + lc;
#pragma unroll
  for (int i = 0; i < 4; i++) {
    float4 v = *(const float4*)(ip + i * 4);
    L[lr][lc + i * 4 + 0] = v.x;
    L[lr][lc + i * 4 + 1] = v.y;
    L[lr][lc + i * 4 + 2] = v.z;
    L[lr][lc + i * 4 + 3] = v.w;
  }
  __syncthreads();
  const int oc = t >> 2, om = (t & 3) * 16;
  union { f16 hh[16]; uint4 u[2]; } pk;
#pragma unroll
  for (int jx = 0; jx < 16; jx++) pk.hh[jx] = f2h(L[om + jx][oc]);
  f16* op = Wt + ((size_t)which * DM + h * DK + oc) * DM + m0 + om;
  *(uint4*)op = pk.u[0];
  *(uint4*)(op + 8) = pk.u[1];
}

// WO[n][d] -> Wot[d][n]
__global__ __launch_bounds__(256) void tcast_wo_kernel(const float* __restrict__ WO,
                                                       f16* __restrict__ Wt) {
  __shared__ float L[64][65];
  const int n0 = blockIdx.x * 64, d0 = blockIdx.y * 64;
  const int t = threadIdx.x;
  const int lr = t >> 2, lc = (t & 3) * 16;
  const float* ip = WO + (size_t)(n0 + lr) * DM + d0 + lc;
#pragma unroll
  for (int i = 0; i < 4; i++) {
    float4 v = *(const float4*)(ip + i * 4);
    L[lr][lc + i * 4 + 0] = v.x;
    L[lr][lc + i * 4 + 1] = v.y;
    L[lr][lc + i * 4 + 2] = v.z;
    L[lr][lc + i * 4 + 3] = v.w;
  }
  __syncthreads();
  const int oc = t >> 2, om = (t & 3) * 16;
  union { f16 hh[16]; uint4 u[2]; } pk;
#pragma unroll
  for (int jx = 0; jx < 16; jx++) pk.hh[jx] = f2h(L[om + jx][oc]);
  f16* op = Wt + (size_t)(d0 + oc) * DM + n0 + om;
  *(uint4*)op = pk.u[0];
  *(uint4*)(op + 8) = pk.u[1];
}

// ---------------- GEMM (m97 structure): C[M,N] = A[M,K] * Bt[N,K]^T ----------------
template <int MODE>
__global__ __launch_bounds__(256) void gemm_bt_kernel(const f16* __restrict__ A,
                                                      const f16* __restrict__ Bt,
                                                      float* __restrict__ Cf,
                                                      f16* __restrict__ Cq,
                                                      f16* __restrict__ Vt, int N) {
  constexpr int K = 768;
  __shared__ __align__(16) f16 As[128 * 32];  // unpadded: global_load_lds lane order
  __shared__ __align__(16) f16 Bs[128 * 32];
  const int t = threadIdx.x;
  const int m0 = blockIdx.y * 128, n0 = blockIdx.x * 128;
  const int lane = t & 63, wave = t >> 6;
  const int l15 = lane & 15, quad = lane >> 4;
  const int m_off = (wave & 1) * 64, n_off = (wave >> 1) * 64;
  const int r0 = t >> 2, ko = (t & 3) * 8;
  const f16* Ag0 = A + (size_t)(m0 + r0) * K + ko;
  const f16* Ag1 = A + (size_t)(m0 + r0 + 64) * K + ko;
  const f16* Bg0 = Bt + (size_t)(n0 + r0) * K + ko;
  const f16* Bg1 = Bt + (size_t)(n0 + r0 + 64) * K + ko;
  f16* lA0 = &As[t * 8];
  f16* lA1 = &As[(t + 256) * 8];
  f16* lB0 = &Bs[t * 8];
  f16* lB1 = &Bs[(t + 256) * 8];

  f32x4 acc[4][4];
  const f32x4 z4 = {0.f, 0.f, 0.f, 0.f};
  for (int i = 0; i < 4; i++)
    for (int j = 0; j < 4; j++) acc[i][j] = z4;

  for (int kt = 0; kt < K; kt += 32) {
    __syncthreads();
    gl_lds16(Ag0 + kt, lA0);
    gl_lds16(Ag1 + kt, lA1);
    gl_lds16(Bg0 + kt, lB0);
    gl_lds16(Bg1 + kt, lB1);
    __syncthreads();
    f16x8 af[4], bfr[4];
#pragma unroll
    for (int i = 0; i < 4; i++)
      af[i] = *(const f16x8*)&As[(m_off + i * 16 + l15) * 32 + quad * 8];
#pragma unroll
    for (int i = 0; i < 4; i++)
      bfr[i] = *(const f16x8*)&Bs[(n_off + i * 16 + l15) * 32 + quad * 8];
#pragma unroll
    for (int mi = 0; mi < 4; mi++)
#pragma unroll
      for (int ni = 0; ni < 4; ni++)
        acc[mi][ni] = __builtin_amdgcn_mfma_f32_16x16x32_f16(af[mi], bfr[ni],
                                                             acc[mi][ni], 0, 0, 0);
  }

  if (MODE == 0) {
#pragma unroll
    for (int mi = 0; mi < 4; mi++) {
      int row = m0 + m_off + mi * 16 + quad * 4;
#pragma unroll
      for (int ni = 0; ni < 4; ni++) {
        int col = n0 + n_off + ni * 16 + l15;
#pragma unroll
        for (int r = 0; r < 4; r++) Cf[(size_t)(row + r) * N + col] = acc[mi][ni][r];
      }
    }
  } else {
#pragma unroll
    for (int mi = 0; mi < 4; mi++) {
      int srow = m0 + m_off + mi * 16 + quad * 4;
      int bb = srow >> 11, ss = srow & 2047;
#pragma unroll
      for (int ni = 0; ni < 4; ni++) {
        int n = n0 + n_off + ni * 16 + l15;
        int which = n / DM;
        int rr = n - which * DM;
        int h = rr >> 6, kk = rr & 63;
        if (which < 2) {  // Q,K -> [h][b][s][64]
#pragma unroll
          for (int r = 0; r < 4; r++) {
            size_t dst = (size_t)which * HBSD +
                         ((size_t)((h * B_ + bb) * S_) + ss + r) * DK + kk;
            Cq[dst] = f2h(acc[mi][ni][r]);
          }
        } else {  // V -> Vt [h][b][d][s]
          union { f16 hh[4]; uint2 u; } pk;
#pragma unroll
          for (int r = 0; r < 4; r++) pk.hh[r] = f2h(acc[mi][ni][r]);
          *(uint2*)&Vt[((size_t)(h * B_ + bb) * DK + kk) * S_ + ss] = pk.u;
        }
      }
    }
  }
}

// ---------------- flash attention v5: kv-split + XCD pinning + lean softmax -------
// 1536 blocks (1-D). bid&7 = XCD; each XCD owns 6 (h,b) pairs entirely so K/V live
// in its L2. Per block: 64 q rows, wave w takes kv tiles w, w+4, ... (no barriers);
// 2-barrier merge epilogue. Softmax in exp2 domain; rescale gated on max-change.
__global__ __launch_bounds__(256) void flash_kernel(const f16* __restrict__ Qg,
                                                    const f16* __restrict__ Kg,
                                                    const f16* __restrict__ Vtg,
                                                    f16* __restrict__ MH) {
  __shared__ __align__(16) f16 Om[4][64][72];
  __shared__ __align__(16) f16 Ps[4][16 * 72];
  __shared__ float Ms[4][64], Ls[4][64];

  const int t = threadIdx.x, lane = t & 63, w = t >> 6;
  const int l15 = lane & 15, quad = lane >> 4;

  const int bid = blockIdx.x;
  const int xcd = bid & 7, gi = bid >> 3;
  const int hb = xcd * 6 + (gi >> 5);   // (h*B+b): 6 pairs per XCD
  const int qb = 31 - (gi & 31);        // longest-first
  const int h = hb >> 2, b = hb & 3;
  const size_t base = (size_t)hb * S_ * DK;
  const f16* Qp = Qg + base;
  const f16* Kp = Kg + base;
  const f16* Vp = Vtg + base;  // [d][S_]
  const int q0 = qb * 64;
  const float c2 = 0.18033688011f;  // log2(e)/8: p = 2^(s*c2 - m2)

  // Q fragments for all 4 q-groups, direct from global
  f16x8 aq[4][2];
#pragma unroll
  for (int qg = 0; qg < 4; qg++) {
    const f16* qrow = Qp + (size_t)(q0 + qg * 16 + l15) * DK + quad * 8;
    aq[qg][0] = *(const f16x8*)(qrow);
    aq[qg][1] = *(const f16x8*)(qrow + 32);
  }

  float m_s[4] = {-1e30f, -1e30f, -1e30f, -1e30f};  // exp2 domain
  float l_s[4] = {0.f, 0.f, 0.f, 0.f};
  f32x4 oacc[4][4];
  const f32x4 z4 = {0.f, 0.f, 0.f, 0.f};
#pragma unroll
  for (int qg = 0; qg < 4; qg++)
#pragma unroll
    for (int ni = 0; ni < 4; ni++) oacc[qg][ni] = z4;

  for (int kt = w; kt <= qb; kt += 4) {
    const int kv0 = kt * 64;
    // phase 1: K fragments + all-qg QK (32 independent MFMAs; kf dies after)
    f16x8 kf[4][2];
#pragma unroll
    for (int mi = 0; mi < 4; mi++) {
      const f16* kp = Kp + (size_t)(kv0 + mi * 16 + l15) * DK + quad * 8;
      kf[mi][0] = *(const f16x8*)(kp);
      kf[mi][1] = *(const f16x8*)(kp + 32);
    }
    f32x4 sa[4][4];
#pragma unroll
    for (int qg = 0; qg < 4; qg++)
#pragma unroll
      for (int mi = 0; mi < 4; mi++)
        sa[qg][mi] =
            __builtin_amdgcn_mfma_f32_16x16x32_f16(kf[mi][0], aq[qg][0], z4, 0, 0, 0);
#pragma unroll
    for (int qg = 0; qg < 4; qg++)
#pragma unroll
      for (int mi = 0; mi < 4; mi++)
        sa[qg][mi] = __builtin_amdgcn_mfma_f32_16x16x32_f16(kf[mi][1], aq[qg][1],
                                                            sa[qg][mi], 0, 0, 0);

    // phase 2: issue V loads early; consumed after softmax
    f16x8 vf[4][2];
#pragma unroll
    for (int ni = 0; ni < 4; ni++) {
      const f16* vp = Vp + (size_t)(ni * 16 + l15) * S_ + kv0 + quad * 8;
      vf[ni][0] = *(const f16x8*)(vp);
      vf[ni][1] = *(const f16x8*)(vp + 32);
    }
    const bool diag = (kt == qb);

    // phase 3: per-qg softmax + P store + PV
#pragma unroll
    for (int qg = 0; qg < 4; qg++) {
      if (diag) {
        int qgl = q0 + qg * 16 + l15;
#pragma unroll
        for (int mi = 0; mi < 4; mi++)
#pragma unroll
          for (int r = 0; r < 4; r++)
            if (kv0 + mi * 16 + quad * 4 + r > qgl) sa[qg][mi][r] = -1e30f;
      }

      float mx =
          fmaxf(fmaxf(fmaxf(sa[qg][0][0], sa[qg][0][1]), fmaxf(sa[qg][0][2], sa[qg][0][3])),
                fmaxf(fmaxf(sa[qg][1][0], sa[qg][1][1]), fmaxf(sa[qg][1][2], sa[qg][1][3])));
      float mx2 =
          fmaxf(fmaxf(fmaxf(sa[qg][2][0], sa[qg][2][1]), fmaxf(sa[qg][2][2], sa[qg][2][3])),
                fmaxf(fmaxf(sa[qg][3][0], sa[qg][3][1]), fmaxf(sa[qg][3][2], sa[qg][3][3])));
      mx = fmaxf(mx, mx2);
      mx = fmaxf(mx, __shfl_xor(mx, 16));
      mx = fmaxf(mx, __shfl_xor(mx, 32));
      float m2old = m_s[qg];
      float m2 = fmaxf(m2old, mx * c2);
      m_s[qg] = m2;
      unsigned long long chg = __ballot(m2 > m2old);

      float rs = 0.f;
#pragma unroll
      for (int mi = 0; mi < 4; mi++)
#pragma unroll
        for (int r = 0; r < 4; r++) {
          float p = __builtin_exp2f(fmaf(sa[qg][mi][r], c2, -m2));
          sa[qg][mi][r] = p;
          rs += p;
        }
      rs += __shfl_xor(rs, 16);
      rs += __shfl_xor(rs, 32);

      if (chg) {  // wave-uniform: max moved for some q column
        float alpha = __builtin_exp2f(m2old - m2);
        l_s[qg] = l_s[qg] * alpha + rs;
        float ar[4];
#pragma unroll
        for (int r = 0; r < 4; r++) ar[r] = __shfl(alpha, quad * 4 + r);
#pragma unroll
        for (int ni = 0; ni < 4; ni++)
#pragma unroll
          for (int r = 0; r < 4; r++) oacc[qg][ni][r] *= ar[r];
      } else {
        l_s[qg] += rs;
      }

      // P^T -> per-wave LDS slice in A-frag order
#pragma unroll
      for (int mi = 0; mi < 4; mi++) {
        union { f16 hh[4]; uint2 u; } pk;
#pragma unroll
        for (int r = 0; r < 4; r++) pk.hh[r] = f2h(sa[qg][mi][r]);
        *(uint2*)&Ps[w][l15 * 72 + mi * 16 + quad * 4] = pk.u;
      }

      // O += P V
#pragma unroll
      for (int kc2 = 0; kc2 < 2; kc2++) {
        f16x8 ap = *(const f16x8*)&Ps[w][l15 * 72 + kc2 * 32 + quad * 8];
#pragma unroll
        for (int ni = 0; ni < 4; ni++)
          oacc[qg][ni] = __builtin_amdgcn_mfma_f32_16x16x32_f16(ap, vf[ni][kc2],
                                                               oacc[qg][ni], 0, 0, 0);
      }
    }
  }

  // ---- merge epilogue (2 barriers) ----
  if (quad == 0) {
#pragma unroll
    for (int qg = 0; qg < 4; qg++) {
      Ms[w][qg * 16 + l15] = m_s[qg];
      Ls[w][qg * 16 + l15] = l_s[qg];
    }
  }
  __syncthreads();

#pragma unroll
  for (int qg = 0; qg < 4; qg++) {
    int qi = qg * 16 + l15;
    float M = fmaxf(fmaxf(Ms[0][qi], Ms[1][qi]), fmaxf(Ms[2][qi], Ms[3][qi]));
    float scq = __builtin_exp2f(m_s[qg] - M);
    float sc[4];
#pragma unroll
    for (int r = 0; r < 4; r++) sc[r] = __shfl(scq, quad * 4 + r);
#pragma unroll
    for (int ni = 0; ni < 4; ni++)
#pragma unroll
      for (int r = 0; r < 4; r++)
        Om[w][qg * 16 + quad * 4 + r][ni * 16 + l15] = f2h(oacc[qg][ni][r] * sc[r]);
  }
  __syncthreads();

  {
    int ql = w * 16 + l15;
    float M = fmaxf(fmaxf(Ms[0][ql], Ms[1][ql]), fmaxf(Ms[2][ql], Ms[3][ql]));
    float L = Ls[0][ql] * __builtin_exp2f(Ms[0][ql] - M) +
              Ls[1][ql] * __builtin_exp2f(Ms[1][ql] - M) +
              Ls[2][ql] * __builtin_exp2f(Ms[2][ql] - M) +
              Ls[3][ql] * __builtin_exp2f(Ms[3][ql] - M);
    float linv = 1.0f / L;
    float acc[16];
#pragma unroll
    for (int j = 0; j < 16; j++) acc[j] = 0.f;
#pragma unroll
    for (int wp = 0; wp < 4; wp++) {
      f16x8 o0 = *(const f16x8*)&Om[wp][ql][quad * 16];
      f16x8 o1 = *(const f16x8*)&Om[wp][ql][quad * 16 + 8];
#pragma unroll
      for (int j = 0; j < 8; j++) {
        acc[j] += (float)o0[j];
        acc[8 + j] += (float)o1[j];
      }
    }
    union { f16 h[16]; uint4 u[2]; } pk;
#pragma unroll
    for (int j = 0; j < 16; j++) pk.h[j] = f2h(acc[j] * linv);
    f16* dst = MH + ((size_t)b * S_ + q0 + ql) * DM + h * DK + quad * 16;
    *(uint4*)(dst) = pk.u[0];
    *(uint4*)(dst + 8) = pk.u[1];
  }
}

// ---------------- launch ----------------

extern "C" void kernel_launch(void* const* d_in, const int* in_sizes, int n_in,
                              void* d_out, int out_size, void* d_ws, size_t ws_size,
                              hipStream_t stream) {
  const float* residual = (const float*)d_in[0];
  const float* WQ = (const float*)d_in[1];
  const float* WK = (const float*)d_in[2];
  const float* WV = (const float*)d_in[3];
  const float* WO = (const float*)d_in[4];
  float* out = (float*)d_out;

  char* ws = (char*)d_ws;
  size_t off = 0;
  auto alloc = [&](size_t bytes) {
    void* p = ws + off;
    off += (bytes + 255) & ~(size_t)255;
    return p;
  };
  f16* xb = (f16*)alloc((size_t)B_ * S_ * DM * 2);   // 12.6 MB
  f16* wqkv = (f16*)alloc((size_t)3 * DM * DM * 2);  // 3.5 MB
  f16* wot = (f16*)alloc((size_t)DM * DM * 2);       // 1.2 MB
  f16* qk = (f16*)alloc(2 * HBSD * 2);               // 25.2 MB (Q,K)
  f16* vt = (f16*)alloc(HBSD * 2);                   // 12.6 MB (V^T)
  f16* mh = (f16*)alloc((size_t)B_ * S_ * DM * 2);   // 12.6 MB

  cast_x_kernel<<<(B_ * S_ * DM / 4 + 255) / 256, 256, 0, stream>>>(residual, xb,
                                                                    B_ * S_ * DM / 4);
  tcast_qkv_kernel<<<dim3(DM / 64, 3, H_), 256, 0, stream>>>(WQ, WK, WV, wqkv);
  tcast_wo_kernel<<<dim3(DM / 64, DM / 64), 256, 0, stream>>>(WO, wot);

  gemm_bt_kernel<1><<<dim3(3 * DM / 128, B_ * S_ / 128), 256, 0, stream>>>(
      xb, wqkv, nullptr, qk, vt, 3 * DM);

  flash_kernel<<<1536, 256, 0, stream>>>(qk, qk + HBSD, vt, mh);

  gemm_bt_kernel<0><<<dim3(DM / 128, B_ * S_ / 128), 256, 0, stream>>>(
      mh, wot, out, nullptr, nullptr, DM);
}

// Round 8
// 269.872 us; speedup vs baseline: 1.5872x; 1.0203x over previous
//
#include <hip/hip_runtime.h>

typedef _Float16 f16;
typedef _Float16 f16x8 __attribute__((ext_vector_type(8)));
typedef float f32x4 __attribute__((ext_vector_type(4)));

#define H_ 12
#define B_ 4
#define S_ 2048
#define DM 768
#define DK 64
#define HBSD ((size_t)H_ * B_ * S_ * DK)

__device__ __forceinline__ f16 f2h(float f) { return (f16)f; }

// async global->LDS, 16B per lane. LDS dest must be wave-uniform base + lane*16.
__device__ __forceinline__ void gl_lds16(const f16* g, f16* l) {
  __builtin_amdgcn_global_load_lds(
      (const __attribute__((address_space(1))) void*)g,
      (__attribute__((address_space(3))) void*)l, 16, 0, 0);
}

// ---------------- prep kernels ----------------

__global__ __launch_bounds__(256) void cast_x_kernel(const float* __restrict__ x,
                                                     f16* __restrict__ xb, int n4) {
  int i = blockIdx.x * 256 + threadIdx.x;
  if (i < n4) {
    float4 v = ((const float4*)x)[i];
    union { f16 h[4]; uint2 u; } pk;
    pk.h[0] = f2h(v.x); pk.h[1] = f2h(v.y); pk.h[2] = f2h(v.z); pk.h[3] = f2h(v.w);
    ((uint2*)xb)[i] = pk.u;
  }
}

// W_{which}[h][m][c] -> Wt[(which*768 + h*64 + c)][m]  (coalesced LDS transpose)
__global__ __launch_bounds__(256) void tcast_qkv_kernel(const float* __restrict__ WQ,
                                                        const float* __restrict__ WK,
                                                        const float* __restrict__ WV,
                                                        f16* __restrict__ Wt) {
  __shared__ float L[64][65];
  const int m0 = blockIdx.x * 64, which = blockIdx.y, h = blockIdx.z;
  const float* in = (which == 0 ? WQ : which == 1 ? WK : WV) + (size_t)h * DM * DK;
  const int t = threadIdx.x;
  const int lr = t >> 2, lc = (t & 3) * 16;
  const float* ip = in + (size_t)(m0 + lr) * DK + lc;
#pragma unroll
  for (int i = 0; i < 4; i++) {
    float4 v = *(const float4*)(ip + i * 4);
    L[lr][lc + i * 4 + 0] = v.x;
    L[lr][lc + i * 4 + 1] = v.y;
    L[lr][lc + i * 4 + 2] = v.z;
    L[lr][lc + i * 4 + 3] = v.w;
  }
  __syncthreads();
  const int oc = t >> 2, om = (t & 3) * 16;
  union { f16 hh[16]; uint4 u[2]; } pk;
#pragma unroll
  for (int jx = 0; jx < 16; jx++) pk.hh[jx] = f2h(L[om + jx][oc]);
  f16* op = Wt + ((size_t)which * DM + h * DK + oc) * DM + m0 + om;
  *(uint4*)op = pk.u[0];
  *(uint4*)(op + 8) = pk.u[1];
}

// WO[n][d] -> Wot[d][n]
__global__ __launch_bounds__(256) void tcast_wo_kernel(const float* __restrict__ WO,
                                                       f16* __restrict__ Wt) {
  __shared__ float L[64][65];
  const int n0 = blockIdx.x * 64, d0 = blockIdx.y * 64;
  const int t = threadIdx.x;
  const int lr = t >> 2, lc = (t & 3) * 16;
  const float* ip = WO + (size_t)(n0 + lr) * DM + d0 + lc;
#pragma unroll
  for (int i = 0; i < 4; i++) {
    float4 v = *(const float4*)(ip + i * 4);
    L[lr][lc + i * 4 + 0] = v.x;
    L[lr][lc + i * 4 + 1] = v.y;
    L[lr][lc + i * 4 + 2] = v.z;
    L[lr][lc + i * 4 + 3] = v.w;
  }
  __syncthreads();
  const int oc = t >> 2, om = (t & 3) * 16;
  union { f16 hh[16]; uint4 u[2]; } pk;
#pragma unroll
  for (int jx = 0; jx < 16; jx++) pk.hh[jx] = f2h(L[om + jx][oc]);
  f16* op = Wt + (size_t)(d0 + oc) * DM + n0 + om;
  *(uint4*)op = pk.u[0];
  *(uint4*)(op + 8) = pk.u[1];
}

// ---------------- GEMM, BK=64 2-slab: C[M,N] = A[M,K] * Bt[N,K]^T ----------------
// LDS layout per matrix: [slab s][row 128][32 cols]; slab stride 128*32 = 4096.
template <int MODE>
__global__ __launch_bounds__(256) void gemm_bt_kernel(const f16* __restrict__ A,
                                                      const f16* __restrict__ Bt,
                                                      float* __restrict__ Cf,
                                                      f16* __restrict__ Cq,
                                                      f16* __restrict__ Vt, int N) {
  constexpr int K = 768;
  __shared__ __align__(16) f16 As[2 * 128 * 32];
  __shared__ __align__(16) f16 Bs[2 * 128 * 32];
  const int t = threadIdx.x;
  const int m0 = blockIdx.y * 128, n0 = blockIdx.x * 128;
  const int lane = t & 63, wave = t >> 6;
  const int l15 = lane & 15, quad = lane >> 4;
  const int m_off = (wave & 1) * 64, n_off = (wave >> 1) * 64;
  const int r0 = t >> 2, ko = (t & 3) * 8;
  const f16* Ag0 = A + (size_t)(m0 + r0) * K + ko;
  const f16* Ag1 = A + (size_t)(m0 + r0 + 64) * K + ko;
  const f16* Bg0 = Bt + (size_t)(n0 + r0) * K + ko;
  const f16* Bg1 = Bt + (size_t)(n0 + r0 + 64) * K + ko;

  f32x4 acc[4][4];
  const f32x4 z4 = {0.f, 0.f, 0.f, 0.f};
  for (int i = 0; i < 4; i++)
    for (int j = 0; j < 4; j++) acc[i][j] = z4;

  for (int kt = 0; kt < K; kt += 64) {
    __syncthreads();
#pragma unroll
    for (int s = 0; s < 2; s++) {
      gl_lds16(Ag0 + kt + s * 32, &As[s * 4096 + t * 8]);
      gl_lds16(Ag1 + kt + s * 32, &As[s * 4096 + 2048 + t * 8]);
      gl_lds16(Bg0 + kt + s * 32, &Bs[s * 4096 + t * 8]);
      gl_lds16(Bg1 + kt + s * 32, &Bs[s * 4096 + 2048 + t * 8]);
    }
    __syncthreads();
#pragma unroll
    for (int s = 0; s < 2; s++) {
      f16x8 af[4], bfr[4];
#pragma unroll
      for (int i = 0; i < 4; i++)
        af[i] = *(const f16x8*)&As[s * 4096 + (m_off + i * 16 + l15) * 32 + quad * 8];
#pragma unroll
      for (int i = 0; i < 4; i++)
        bfr[i] = *(const f16x8*)&Bs[s * 4096 + (n_off + i * 16 + l15) * 32 + quad * 8];
#pragma unroll
      for (int mi = 0; mi < 4; mi++)
#pragma unroll
        for (int ni = 0; ni < 4; ni++)
          acc[mi][ni] = __builtin_amdgcn_mfma_f32_16x16x32_f16(af[mi], bfr[ni],
                                                               acc[mi][ni], 0, 0, 0);
    }
  }

  if (MODE == 0) {
#pragma unroll
    for (int mi = 0; mi < 4; mi++) {
      int row = m0 + m_off + mi * 16 + quad * 4;
#pragma unroll
      for (int ni = 0; ni < 4; ni++) {
        int col = n0 + n_off + ni * 16 + l15;
#pragma unroll
        for (int r = 0; r < 4; r++) Cf[(size_t)(row + r) * N + col] = acc[mi][ni][r];
      }
    }
  } else {
#pragma unroll
    for (int mi = 0; mi < 4; mi++) {
      int srow = m0 + m_off + mi * 16 + quad * 4;
      int bb = srow >> 11, ss = srow & 2047;
#pragma unroll
      for (int ni = 0; ni < 4; ni++) {
        int n = n0 + n_off + ni * 16 + l15;
        int which = n / DM;
        int rr = n - which * DM;
        int h = rr >> 6, kk = rr & 63;
        if (which < 2) {  // Q,K -> [h][b][s][64]
#pragma unroll
          for (int r = 0; r < 4; r++) {
            size_t dst = (size_t)which * HBSD +
                         ((size_t)((h * B_ + bb) * S_) + ss + r) * DK + kk;
            Cq[dst] = f2h(acc[mi][ni][r]);
          }
        } else {  // V -> Vt [h][b][d][s]
          union { f16 hh[4]; uint2 u; } pk;
#pragma unroll
          for (int r = 0; r < 4; r++) pk.hh[r] = f2h(acc[mi][ni][r]);
          *(uint2*)&Vt[((size_t)(h * B_ + bb) * DK + kk) * S_ + ss] = pk.u;
        }
      }
    }
  }
}

// ---------------- flash attention v6b: q-split FA2, O^T, LDS K/V slabs ------------
// 1536 blocks; bid&7 = XCD (6 (h,b) pairs per XCD -> K/V L2-local); qb longest-first.
// Block owns 64 q; wave w owns q rows w*16..+15 (oacc 16 regs, no merge).
// K/V tiles staged once per tile via global_load_lds into [2][64][32] slabs
// (slab stride 64*32 = 2048 — the R7 bug was a 4096 stride here).
// S^T = K·Q^T (softmax state per-lane, q=l15); O^T = mfma(vf, ap) so alpha/linv
// rescales are per-lane (no cross-lane broadcasts anywhere).
__global__ __launch_bounds__(256, 3) void flash_kernel(const f16* __restrict__ Qg,
                                                       const f16* __restrict__ Kg,
                                                       const f16* __restrict__ Vtg,
                                                       f16* __restrict__ MH) {
  __shared__ __align__(16) f16 Ksh[2 * 64 * 32];  // [kc2][kv][32]
  __shared__ __align__(16) f16 Vsh[2 * 64 * 32];  // [kc2][v][32] (cols = kv)
  __shared__ __align__(16) f16 Ps[4][16 * 72];

  const int t = threadIdx.x, lane = t & 63, w = t >> 6;
  const int l15 = lane & 15, quad = lane >> 4;
  const int bid = blockIdx.x;
  const int xcd = bid & 7, gi = bid >> 3;
  const int hb = xcd * 6 + (gi >> 5);
  const int qb = 31 - (gi & 31);
  const int h = hb >> 2, b = hb & 3;
  const size_t base = (size_t)hb * S_ * DK;
  const f16* Qp = Qg + base;
  const f16* Kp = Kg + base;
  const f16* Vp = Vtg + base;  // [d][S_]
  const int q0 = qb * 64;
  const float c2 = 0.18033688011f;  // log2(e)/8

  // this wave's 16-q A-fragment, once from global
  f16x8 aq[2];
  {
    const f16* qrow = Qp + (size_t)(q0 + w * 16 + l15) * DK + quad * 8;
    aq[0] = *(const f16x8*)(qrow);
    aq[1] = *(const f16x8*)(qrow + 32);
  }
  const int qlane = q0 + w * 16 + l15;  // this lane's q column

  const int srow = t >> 2, scol = (t & 3) * 8;
  const f16* Kst = Kp + (size_t)srow * DK + scol;
  const f16* Vst = Vp + (size_t)srow * S_ + scol;

  float m_s = -1e30f, l_s = 0.f;
  f32x4 oacc[4];
  const f32x4 z4 = {0.f, 0.f, 0.f, 0.f};
#pragma unroll
  for (int ni = 0; ni < 4; ni++) oacc[ni] = z4;

  for (int kt = 0; kt <= qb; kt++) {
    const int kv0 = kt * 64;
    __syncthreads();  // prev tile's LDS reads complete
    gl_lds16(Kst + (size_t)kv0 * DK, &Ksh[t * 8]);
    gl_lds16(Kst + (size_t)kv0 * DK + 32, &Ksh[2048 + t * 8]);
    gl_lds16(Vst + kv0, &Vsh[t * 8]);
    gl_lds16(Vst + kv0 + 32, &Vsh[2048 + t * 8]);
    __syncthreads();  // vmcnt(0) drain -> LDS valid

    // S^T[kv][q=l15]
    f32x4 sa[4];
#pragma unroll
    for (int mi = 0; mi < 4; mi++) {
      f16x8 k0 = *(const f16x8*)&Ksh[(mi * 16 + l15) * 32 + quad * 8];
      sa[mi] = __builtin_amdgcn_mfma_f32_16x16x32_f16(k0, aq[0], z4, 0, 0, 0);
    }
#pragma unroll
    for (int mi = 0; mi < 4; mi++) {
      f16x8 k1 = *(const f16x8*)&Ksh[2048 + (mi * 16 + l15) * 32 + quad * 8];
      sa[mi] = __builtin_amdgcn_mfma_f32_16x16x32_f16(k1, aq[1], sa[mi], 0, 0, 0);
    }

    if (kt == qb) {  // diagonal: mask kv > q
#pragma unroll
      for (int mi = 0; mi < 4; mi++)
#pragma unroll
        for (int r = 0; r < 4; r++)
          if (kv0 + mi * 16 + quad * 4 + r > qlane) sa[mi][r] = -1e30f;
    }

    // per-lane online softmax over this lane's q column (reduce across quads)
    float mx = fmaxf(fmaxf(fmaxf(sa[0][0], sa[0][1]), fmaxf(sa[0][2], sa[0][3])),
                     fmaxf(fmaxf(sa[1][0], sa[1][1]), fmaxf(sa[1][2], sa[1][3])));
    float mx2 = fmaxf(fmaxf(fmaxf(sa[2][0], sa[2][1]), fmaxf(sa[2][2], sa[2][3])),
                      fmaxf(fmaxf(sa[3][0], sa[3][1]), fmaxf(sa[3][2], sa[3][3])));
    mx = fmaxf(mx, mx2);
    mx = fmaxf(mx, __shfl_xor(mx, 16));
    mx = fmaxf(mx, __shfl_xor(mx, 32));
    float m2old = m_s;
    float m2 = fmaxf(m2old, mx * c2);
    m_s = m2;
    float alpha = __builtin_exp2f(m2old - m2);
    float rs = 0.f;
#pragma unroll
    for (int mi = 0; mi < 4; mi++)
#pragma unroll
      for (int r = 0; r < 4; r++) {
        float p = __builtin_exp2f(fmaf(sa[mi][r], c2, -m2));
        sa[mi][r] = p;
        rs += p;
      }
    rs += __shfl_xor(rs, 16);
    rs += __shfl_xor(rs, 32);
    l_s = l_s * alpha + rs;

    // O^T rescale: col q = l15 -> per-lane multiply, no broadcast
#pragma unroll
    for (int ni = 0; ni < 4; ni++)
#pragma unroll
      for (int r = 0; r < 4; r++) oacc[ni][r] *= alpha;

    // P^T C-layout -> Ps[q][kv] (A/B-frag order), per-wave slice
#pragma unroll
    for (int mi = 0; mi < 4; mi++) {
      union { f16 hh[4]; uint2 u; } pk;
#pragma unroll
      for (int r = 0; r < 4; r++) pk.hh[r] = f2h(sa[mi][r]);
      *(uint2*)&Ps[w][l15 * 72 + mi * 16 + quad * 4] = pk.u;
    }

    // O^T += V^T P^T : mfma(A=vf rows v, B=ap rows q) -> D[v][q], col q=l15
#pragma unroll
    for (int kc2 = 0; kc2 < 2; kc2++) {
      f16x8 ap = *(const f16x8*)&Ps[w][l15 * 72 + kc2 * 32 + quad * 8];
#pragma unroll
      for (int ni = 0; ni < 4; ni++) {
        f16x8 vf = *(const f16x8*)&Vsh[kc2 * 2048 + (ni * 16 + l15) * 32 + quad * 8];
        oacc[ni] = __builtin_amdgcn_mfma_f32_16x16x32_f16(vf, ap, oacc[ni], 0, 0, 0);
      }
    }
  }

  // epilogue: per-lane normalize, write MH[b][q][h*64+v]; v=ni*16+quad*4+r
  float linv = 1.0f / l_s;
  f16* dst = MH + ((size_t)b * S_ + qlane) * DM + h * DK + quad * 4;
#pragma unroll
  for (int ni = 0; ni < 4; ni++) {
    union { f16 hh[4]; uint2 u; } pk;
#pragma unroll
    for (int r = 0; r < 4; r++) pk.hh[r] = f2h(oacc[ni][r] * linv);
    *(uint2*)(dst + ni * 16) = pk.u;
  }
}

// ---------------- launch ----------------

extern "C" void kernel_launch(void* const* d_in, const int* in_sizes, int n_in,
                              void* d_out, int out_size, void* d_ws, size_t ws_size,
                              hipStream_t stream) {
  const float* residual = (const float*)d_in[0];
  const float* WQ = (const float*)d_in[1];
  const float* WK = (const float*)d_in[2];
  const float* WV = (const float*)d_in[3];
  const float* WO = (const float*)d_in[4];
  float* out = (float*)d_out;

  char* ws = (char*)d_ws;
  size_t off = 0;
  auto alloc = [&](size_t bytes) {
    void* p = ws + off;
    off += (bytes + 255) & ~(size_t)255;
    return p;
  };
  f16* xb = (f16*)alloc((size_t)B_ * S_ * DM * 2);   // 12.6 MB
  f16* wqkv = (f16*)alloc((size_t)3 * DM * DM * 2);  // 3.5 MB
  f16* wot = (f16*)alloc((size_t)DM * DM * 2);       // 1.2 MB
  f16* qk = (f16*)alloc(2 * HBSD * 2);               // 25.2 MB (Q,K)
  f16* vt = (f16*)alloc(HBSD * 2);                   // 12.6 MB (V^T)
  f16* mh = (f16*)alloc((size_t)B_ * S_ * DM * 2);   // 12.6 MB

  cast_x_kernel<<<(B_ * S_ * DM / 4 + 255) / 256, 256, 0, stream>>>(residual, xb,
                                                                    B_ * S_ * DM / 4);
  tcast_qkv_kernel<<<dim3(DM / 64, 3, H_), 256, 0, stream>>>(WQ, WK, WV, wqkv);
  tcast_wo_kernel<<<dim3(DM / 64, DM / 64), 256, 0, stream>>>(WO, wot);

  gemm_bt_kernel<1><<<dim3(3 * DM / 128, B_ * S_ / 128), 256, 0, stream>>>(
      xb, wqkv, nullptr, qk, vt, 3 * DM);

  flash_kernel<<<1536, 256, 0, stream>>>(qk, qk + HBSD, vt, mh);

  gemm_bt_kernel<0><<<dim3(DM / 128, B_ * S_ / 128), 256, 0, stream>>>(
      mh, wot, out, nullptr, nullptr, DM);
}

// Round 9
// 229.321 us; speedup vs baseline: 1.8679x; 1.1768x over previous
//
#include <hip/hip_runtime.h>

typedef _Float16 f16;
typedef _Float16 f16x8 __attribute__((ext_vector_type(8)));
typedef float f32x4 __attribute__((ext_vector_type(4)));

#define H_ 12
#define B_ 4
#define S_ 2048
#define DM 768
#define DK 64
#define HBSD ((size_t)H_ * B_ * S_ * DK)

__device__ __forceinline__ f16 f2h(float f) { return (f16)f; }

// async global->LDS, 16B per lane. LDS dest must be wave-uniform base + lane*16.
__device__ __forceinline__ void gl_lds16(const f16* g, f16* l) {
  __builtin_amdgcn_global_load_lds(
      (const __attribute__((address_space(1))) void*)g,
      (__attribute__((address_space(3))) void*)l, 16, 0, 0);
}

// ---------------- prep kernels ----------------

__global__ __launch_bounds__(256) void cast_x_kernel(const float* __restrict__ x,
                                                     f16* __restrict__ xb, int n4) {
  int i = blockIdx.x * 256 + threadIdx.x;
  if (i < n4) {
    float4 v = ((const float4*)x)[i];
    union { f16 h[4]; uint2 u; } pk;
    pk.h[0] = f2h(v.x); pk.h[1] = f2h(v.y); pk.h[2] = f2h(v.z); pk.h[3] = f2h(v.w);
    ((uint2*)xb)[i] = pk.u;
  }
}

// W_{which}[h][m][c] -> Wt[(which*768 + h*64 + c)][m]  (coalesced LDS transpose)
__global__ __launch_bounds__(256) void tcast_qkv_kernel(const float* __restrict__ WQ,
                                                        const float* __restrict__ WK,
                                                        const float* __restrict__ WV,
                                                        f16* __restrict__ Wt) {
  __shared__ float L[64][65];
  const int m0 = blockIdx.x * 64, which = blockIdx.y, h = blockIdx.z;
  const float* in = (which == 0 ? WQ : which == 1 ? WK : WV) + (size_t)h * DM * DK;
  const int t = threadIdx.x;
  const int lr = t >> 2, lc = (t & 3) * 16;
  const float* ip = in + (size_t)(m0 + lr) * DK + lc;
#pragma unroll
  for (int i = 0; i < 4; i++) {
    float4 v = *(const float4*)(ip + i * 4);
    L[lr][lc + i * 4 + 0] = v.x;
    L[lr][lc + i * 4 + 1] = v.y;
    L[lr][lc + i * 4 + 2] = v.z;
    L[lr][lc + i * 4 + 3] = v.w;
  }
  __syncthreads();
  const int oc = t >> 2, om = (t & 3) * 16;
  union { f16 hh[16]; uint4 u[2]; } pk;
#pragma unroll
  for (int jx = 0; jx < 16; jx++) pk.hh[jx] = f2h(L[om + jx][oc]);
  f16* op = Wt + ((size_t)which * DM + h * DK + oc) * DM + m0 + om;
  *(uint4*)op = pk.u[0];
  *(uint4*)(op + 8) = pk.u[1];
}

// WO[n][d] -> Wot[d][n]
__global__ __launch_bounds__(256) void tcast_wo_kernel(const float* __restrict__ WO,
                                                       f16* __restrict__ Wt) {
  __shared__ float L[64][65];
  const int n0 = blockIdx.x * 64, d0 = blockIdx.y * 64;
  const int t = threadIdx.x;
  const int lr = t >> 2, lc = (t & 3) * 16;
  const float* ip = WO + (size_t)(n0 + lr) * DM + d0 + lc;
#pragma unroll
  for (int i = 0; i < 4; i++) {
    float4 v = *(const float4*)(ip + i * 4);
    L[lr][lc + i * 4 + 0] = v.x;
    L[lr][lc + i * 4 + 1] = v.y;
    L[lr][lc + i * 4 + 2] = v.z;
    L[lr][lc + i * 4 + 3] = v.w;
  }
  __syncthreads();
  const int oc = t >> 2, om = (t & 3) * 16;
  union { f16 hh[16]; uint4 u[2]; } pk;
#pragma unroll
  for (int jx = 0; jx < 16; jx++) pk.hh[jx] = f2h(L[om + jx][oc]);
  f16* op = Wt + (size_t)(d0 + oc) * DM + n0 + om;
  *(uint4*)op = pk.u[0];
  *(uint4*)(op + 8) = pk.u[1];
}

// ---------------- GEMM, BK=64 2-slab: C[M,N] = A[M,K] * Bt[N,K]^T ----------------
// LDS layout per matrix: [slab s][row 128][32 cols]; slab stride 128*32 = 4096.
template <int MODE>
__global__ __launch_bounds__(256) void gemm_bt_kernel(const f16* __restrict__ A,
                                                      const f16* __restrict__ Bt,
                                                      float* __restrict__ Cf,
                                                      f16* __restrict__ Cq,
                                                      f16* __restrict__ Vt, int N) {
  constexpr int K = 768;
  __shared__ __align__(16) f16 As[2 * 128 * 32];
  __shared__ __align__(16) f16 Bs[2 * 128 * 32];
  const int t = threadIdx.x;
  const int m0 = blockIdx.y * 128, n0 = blockIdx.x * 128;
  const int lane = t & 63, wave = t >> 6;
  const int l15 = lane & 15, quad = lane >> 4;
  const int m_off = (wave & 1) * 64, n_off = (wave >> 1) * 64;
  const int r0 = t >> 2, ko = (t & 3) * 8;
  const f16* Ag0 = A + (size_t)(m0 + r0) * K + ko;
  const f16* Ag1 = A + (size_t)(m0 + r0 + 64) * K + ko;
  const f16* Bg0 = Bt + (size_t)(n0 + r0) * K + ko;
  const f16* Bg1 = Bt + (size_t)(n0 + r0 + 64) * K + ko;

  f32x4 acc[4][4];
  const f32x4 z4 = {0.f, 0.f, 0.f, 0.f};
  for (int i = 0; i < 4; i++)
    for (int j = 0; j < 4; j++) acc[i][j] = z4;

  for (int kt = 0; kt < K; kt += 64) {
    __syncthreads();
#pragma unroll
    for (int s = 0; s < 2; s++) {
      gl_lds16(Ag0 + kt + s * 32, &As[s * 4096 + t * 8]);
      gl_lds16(Ag1 + kt + s * 32, &As[s * 4096 + 2048 + t * 8]);
      gl_lds16(Bg0 + kt + s * 32, &Bs[s * 4096 + t * 8]);
      gl_lds16(Bg1 + kt + s * 32, &Bs[s * 4096 + 2048 + t * 8]);
    }
    __syncthreads();
#pragma unroll
    for (int s = 0; s < 2; s++) {
      f16x8 af[4], bfr[4];
#pragma unroll
      for (int i = 0; i < 4; i++)
        af[i] = *(const f16x8*)&As[s * 4096 + (m_off + i * 16 + l15) * 32 + quad * 8];
#pragma unroll
      for (int i = 0; i < 4; i++)
        bfr[i] = *(const f16x8*)&Bs[s * 4096 + (n_off + i * 16 + l15) * 32 + quad * 8];
#pragma unroll
      for (int mi = 0; mi < 4; mi++)
#pragma unroll
        for (int ni = 0; ni < 4; ni++)
          acc[mi][ni] = __builtin_amdgcn_mfma_f32_16x16x32_f16(af[mi], bfr[ni],
                                                               acc[mi][ni], 0, 0, 0);
    }
  }

  if (MODE == 0) {
#pragma unroll
    for (int mi = 0; mi < 4; mi++) {
      int row = m0 + m_off + mi * 16 + quad * 4;
#pragma unroll
      for (int ni = 0; ni < 4; ni++) {
        int col = n0 + n_off + ni * 16 + l15;
#pragma unroll
        for (int r = 0; r < 4; r++) Cf[(size_t)(row + r) * N + col] = acc[mi][ni][r];
      }
    }
  } else {
#pragma unroll
    for (int mi = 0; mi < 4; mi++) {
      int srow = m0 + m_off + mi * 16 + quad * 4;
      int bb = srow >> 11, ss = srow & 2047;
#pragma unroll
      for (int ni = 0; ni < 4; ni++) {
        int n = n0 + n_off + ni * 16 + l15;
        int which = n / DM;
        int rr = n - which * DM;
        int h = rr >> 6, kk = rr & 63;
        if (which < 2) {  // Q,K -> [h][b][s][64]
#pragma unroll
          for (int r = 0; r < 4; r++) {
            size_t dst = (size_t)which * HBSD +
                         ((size_t)((h * B_ + bb) * S_) + ss + r) * DK + kk;
            Cq[dst] = f2h(acc[mi][ni][r]);
          }
        } else {  // V -> Vt [h][b][d][s]
          union { f16 hh[4]; uint2 u; } pk;
#pragma unroll
          for (int r = 0; r < 4; r++) pk.hh[r] = f2h(acc[mi][ni][r]);
          *(uint2*)&Vt[((size_t)(h * B_ + bb) * DK + kk) * S_ + ss] = pk.u;
        }
      }
    }
  }
}

// ---------------- flash attention v7: paired q-tiles, shared K/V staging ----------
// 768 blocks; bid&7 = XCD (6 (h,b) pairs per XCD); gi=bid>>3 in [0,96):
// hbi = gi%6, pr = gi/6 in [0,16). Block owns q-tiles qbA=pr and qbB=31-pr of
// (h,b)=hb — exactly 33 job-tiles per block (perfect per-CU MFMA balance).
// One kv walk 0..qbB stages each K/V tile ONCE for both jobs (half the barriers).
// Per wave: 16 q of each job; O^T orientation (per-lane softmax state, q=l15).
__global__ __launch_bounds__(256, 3) void flash_kernel(const f16* __restrict__ Qg,
                                                       const f16* __restrict__ Kg,
                                                       const f16* __restrict__ Vtg,
                                                       f16* __restrict__ MH) {
  __shared__ __align__(16) f16 Ksh[2 * 64 * 32];  // [kc2][kv][32]
  __shared__ __align__(16) f16 Vsh[2 * 64 * 32];  // [kc2][v][32] (cols = kv)
  __shared__ __align__(16) f16 Ps[4][16 * 72];

  const int t = threadIdx.x, lane = t & 63, w = t >> 6;
  const int l15 = lane & 15, quad = lane >> 4;
  const int bid = blockIdx.x;
  const int xcd = bid & 7, gi = bid >> 3;
  const int hbi = gi % 6, pr = gi / 6;
  const int hb = xcd * 6 + hbi;
  const int qbA = pr, qbB = 31 - pr;
  const int h = hb >> 2, b = hb & 3;
  const size_t base = (size_t)hb * S_ * DK;
  const f16* Qp = Qg + base;
  const f16* Kp = Kg + base;
  const f16* Vp = Vtg + base;  // [d][S_]
  const float c2 = 0.18033688011f;  // log2(e)/8

  // Q fragments for both jobs, once from global
  f16x8 aqA[2], aqB[2];
  {
    const f16* qa = Qp + (size_t)(qbA * 64 + w * 16 + l15) * DK + quad * 8;
    aqA[0] = *(const f16x8*)(qa);
    aqA[1] = *(const f16x8*)(qa + 32);
    const f16* qb_ = Qp + (size_t)(qbB * 64 + w * 16 + l15) * DK + quad * 8;
    aqB[0] = *(const f16x8*)(qb_);
    aqB[1] = *(const f16x8*)(qb_ + 32);
  }
  const int qlaneA = qbA * 64 + w * 16 + l15;
  const int qlaneB = qbB * 64 + w * 16 + l15;

  const int srow = t >> 2, scol = (t & 3) * 8;
  const f16* Kst = Kp + (size_t)srow * DK + scol;
  const f16* Vst = Vp + (size_t)srow * S_ + scol;

  float mA = -1e30f, lA = 0.f, mB = -1e30f, lB = 0.f;
  f32x4 oA[4], oB[4];
  const f32x4 z4 = {0.f, 0.f, 0.f, 0.f};
#pragma unroll
  for (int ni = 0; ni < 4; ni++) { oA[ni] = z4; oB[ni] = z4; }

  // per-job tile processing (identical math to the R8-verified path)
  auto do_job = [&](const f16x8* aq, float& m_s, float& l_s, f32x4* oacc,
                    int qlane, int kv0, bool diag) {
    f32x4 sa[4];
#pragma unroll
    for (int mi = 0; mi < 4; mi++) {
      f16x8 k0 = *(const f16x8*)&Ksh[(mi * 16 + l15) * 32 + quad * 8];
      sa[mi] = __builtin_amdgcn_mfma_f32_16x16x32_f16(k0, aq[0], z4, 0, 0, 0);
    }
#pragma unroll
    for (int mi = 0; mi < 4; mi++) {
      f16x8 k1 = *(const f16x8*)&Ksh[2048 + (mi * 16 + l15) * 32 + quad * 8];
      sa[mi] = __builtin_amdgcn_mfma_f32_16x16x32_f16(k1, aq[1], sa[mi], 0, 0, 0);
    }

    if (diag) {  // diagonal tile: mask kv > q
#pragma unroll
      for (int mi = 0; mi < 4; mi++)
#pragma unroll
        for (int r = 0; r < 4; r++)
          if (kv0 + mi * 16 + quad * 4 + r > qlane) sa[mi][r] = -1e30f;
    }

    float mx = fmaxf(fmaxf(fmaxf(sa[0][0], sa[0][1]), fmaxf(sa[0][2], sa[0][3])),
                     fmaxf(fmaxf(sa[1][0], sa[1][1]), fmaxf(sa[1][2], sa[1][3])));
    float mx2 = fmaxf(fmaxf(fmaxf(sa[2][0], sa[2][1]), fmaxf(sa[2][2], sa[2][3])),
                      fmaxf(fmaxf(sa[3][0], sa[3][1]), fmaxf(sa[3][2], sa[3][3])));
    mx = fmaxf(mx, mx2);
    mx = fmaxf(mx, __shfl_xor(mx, 16));
    mx = fmaxf(mx, __shfl_xor(mx, 32));
    float m2old = m_s;
    float m2 = fmaxf(m2old, mx * c2);
    m_s = m2;
    float alpha = __builtin_exp2f(m2old - m2);
    float rs = 0.f;
#pragma unroll
    for (int mi = 0; mi < 4; mi++)
#pragma unroll
      for (int r = 0; r < 4; r++) {
        float p = __builtin_exp2f(fmaf(sa[mi][r], c2, -m2));
        sa[mi][r] = p;
        rs += p;
      }
    rs += __shfl_xor(rs, 16);
    rs += __shfl_xor(rs, 32);
    l_s = l_s * alpha + rs;

#pragma unroll
    for (int ni = 0; ni < 4; ni++)
#pragma unroll
      for (int r = 0; r < 4; r++) oacc[ni][r] *= alpha;

    // P^T -> Ps[q][kv] (per-wave slice; same-wave ds ordering handled by compiler)
#pragma unroll
    for (int mi = 0; mi < 4; mi++) {
      union { f16 hh[4]; uint2 u; } pk;
#pragma unroll
      for (int r = 0; r < 4; r++) pk.hh[r] = f2h(sa[mi][r]);
      *(uint2*)&Ps[w][l15 * 72 + mi * 16 + quad * 4] = pk.u;
    }

    // O^T += V^T P^T
#pragma unroll
    for (int kc2 = 0; kc2 < 2; kc2++) {
      f16x8 ap = *(const f16x8*)&Ps[w][l15 * 72 + kc2 * 32 + quad * 8];
#pragma unroll
      for (int ni = 0; ni < 4; ni++) {
        f16x8 vf = *(const f16x8*)&Vsh[kc2 * 2048 + (ni * 16 + l15) * 32 + quad * 8];
        oacc[ni] = __builtin_amdgcn_mfma_f32_16x16x32_f16(vf, ap, oacc[ni], 0, 0, 0);
      }
    }
  };

  for (int kt = 0; kt <= qbB; kt++) {
    const int kv0 = kt * 64;
    __syncthreads();  // prev tile's LDS reads complete
    gl_lds16(Kst + (size_t)kv0 * DK, &Ksh[t * 8]);
    gl_lds16(Kst + (size_t)kv0 * DK + 32, &Ksh[2048 + t * 8]);
    gl_lds16(Vst + kv0, &Vsh[t * 8]);
    gl_lds16(Vst + kv0 + 32, &Vsh[2048 + t * 8]);
    __syncthreads();  // vmcnt drain -> LDS valid

    do_job(aqB, mB, lB, oB, qlaneB, kv0, kt == qbB);
    if (kt <= qbA) do_job(aqA, mA, lA, oA, qlaneA, kv0, kt == qbA);
  }

  // epilogue: per-lane normalize, write MH[b][q][h*64+v]; v = ni*16+quad*4+r
  {
    float linv = 1.0f / lB;
    f16* dst = MH + ((size_t)b * S_ + qlaneB) * DM + h * DK + quad * 4;
#pragma unroll
    for (int ni = 0; ni < 4; ni++) {
      union { f16 hh[4]; uint2 u; } pk;
#pragma unroll
      for (int r = 0; r < 4; r++) pk.hh[r] = f2h(oB[ni][r] * linv);
      *(uint2*)(dst + ni * 16) = pk.u;
    }
  }
  {
    float linv = 1.0f / lA;
    f16* dst = MH + ((size_t)b * S_ + qlaneA) * DM + h * DK + quad * 4;
#pragma unroll
    for (int ni = 0; ni < 4; ni++) {
      union { f16 hh[4]; uint2 u; } pk;
#pragma unroll
      for (int r = 0; r < 4; r++) pk.hh[r] = f2h(oA[ni][r] * linv);
      *(uint2*)(dst + ni * 16) = pk.u;
    }
  }
}

// ---------------- launch ----------------

extern "C" void kernel_launch(void* const* d_in, const int* in_sizes, int n_in,
                              void* d_out, int out_size, void* d_ws, size_t ws_size,
                              hipStream_t stream) {
  const float* residual = (const float*)d_in[0];
  const float* WQ = (const float*)d_in[1];
  const float* WK = (const float*)d_in[2];
  const float* WV = (const float*)d_in[3];
  const float* WO = (const float*)d_in[4];
  float* out = (float*)d_out;

  char* ws = (char*)d_ws;
  size_t off = 0;
  auto alloc = [&](size_t bytes) {
    void* p = ws + off;
    off += (bytes + 255) & ~(size_t)255;
    return p;
  };
  f16* xb = (f16*)alloc((size_t)B_ * S_ * DM * 2);   // 12.6 MB
  f16* wqkv = (f16*)alloc((size_t)3 * DM * DM * 2);  // 3.5 MB
  f16* wot = (f16*)alloc((size_t)DM * DM * 2);       // 1.2 MB
  f16* qk = (f16*)alloc(2 * HBSD * 2);               // 25.2 MB (Q,K)
  f16* vt = (f16*)alloc(HBSD * 2);                   // 12.6 MB (V^T)
  f16* mh = (f16*)alloc((size_t)B_ * S_ * DM * 2);   // 12.6 MB

  cast_x_kernel<<<(B_ * S_ * DM / 4 + 255) / 256, 256, 0, stream>>>(residual, xb,
                                                                    B_ * S_ * DM / 4);
  tcast_qkv_kernel<<<dim3(DM / 64, 3, H_), 256, 0, stream>>>(WQ, WK, WV, wqkv);
  tcast_wo_kernel<<<dim3(DM / 64, DM / 64), 256, 0, stream>>>(WO, wot);

  gemm_bt_kernel<1><<<dim3(3 * DM / 128, B_ * S_ / 128), 256, 0, stream>>>(
      xb, wqkv, nullptr, qk, vt, 3 * DM);

  flash_kernel<<<768, 256, 0, stream>>>(qk, qk + HBSD, vt, mh);

  gemm_bt_kernel<0><<<dim3(DM / 128, B_ * S_ / 128), 256, 0, stream>>>(
      mh, wot, out, nullptr, nullptr, DM);
}